// Round 2
// 10374.175 us; speedup vs baseline: 1.3821x; 1.3821x over previous
//
#include <hip/hip_runtime.h>
#include <hip/hip_fp16.h>
#include <math.h>

#define Tn 1024
#define Bn 256
#define Hn 120
#define Ln 4
#define NBC 4                 // batch chunks of 64
#define NBLK (Ln*NBC)         // 16 blocks, one per (layer, bc)
#define THR 512               // 8 waves
#define Dd 8                  // ring depth
#define PADI 32
#define KPh 264               // hxT half-stride (16B-aligned rows)

typedef _Float16 f16x8 __attribute__((ext_vector_type(8)));
typedef float    f32x4 __attribute__((ext_vector_type(4)));
typedef unsigned int u32x4 __attribute__((ext_vector_type(4)));
typedef unsigned short ushort_t;

// R16b: R15 + (a) HW transcendentals (v_exp_f32/v_rcp_f32; abs err ~1e-6,
// budget 3.2e-3), (b) vectorized ring producer: cell update writes LDS
// only, then cooperative hxT->ring copy as 960 coalesced dwordx4 sc0sc1
// stores (was 7680 scattered 2B system stores, 4x write amplification),
// (c) l3 output dot parallelized 8 threads/col + shfl reduce.
// Fix vs R16: asm 128-bit operands use ext_vector_type (clang can't take
// HIP's struct uint4 as a "v" input operand).
__device__ ushort_t g_ring[(size_t)3 * Dd * NBC * 64 * Hn]; // [l][slot][bc][b][cell]
__device__ int g_prod[3 * NBC * PADI];
__device__ int g_cons[Ln * NBC * PADI];
__device__ int g_abort;

__global__ __launch_bounds__(256) void init_kernel() {
    int idx = threadIdx.x;
    if (idx < 3 * NBC)  g_prod[idx * PADI] = -1;
    if (idx < Ln * NBC) g_cons[idx * PADI] = -1;
    if (idx == 0)       g_abort = 0;
}

#if __has_builtin(__builtin_amdgcn_exp2f)
__device__ __forceinline__ float hw_exp2(float x) { return __builtin_amdgcn_exp2f(x); }
#else
__device__ __forceinline__ float hw_exp2(float x) { return exp2f(x); }
#endif
#if __has_builtin(__builtin_amdgcn_rcpf)
__device__ __forceinline__ float hw_rcp(float x) { return __builtin_amdgcn_rcpf(x); }
#else
__device__ __forceinline__ float hw_rcp(float x) { return 1.0f / x; }
#endif
#define LOG2E_F 1.44269504f

__device__ __forceinline__ float sigm(float v) {
    return hw_rcp(1.0f + hw_exp2(-LOG2E_F * v));
}
__device__ __forceinline__ float tanh_fast(float v) {
    // tanh(x) = 1 - 2/(exp2(2x*log2e)+1); exact at +-inf, 0 at 0
    return 1.0f - 2.0f * hw_rcp(1.0f + hw_exp2(2.0f * LOG2E_F * v));
}

__device__ __forceinline__ void spin_wait(int* p, int tgt, int& dead, int& pc) {
    if (dead || pc >= tgt) return;
    int guard = 0, v;
    while ((v = __hip_atomic_load(p, __ATOMIC_RELAXED,
                                  __HIP_MEMORY_SCOPE_SYSTEM)) < tgt) {
        __builtin_amdgcn_s_sleep(1);
        if ((++guard & 127) == 0) {
            if (__hip_atomic_load(&g_abort, __ATOMIC_RELAXED,
                                  __HIP_MEMORY_SCOPE_SYSTEM)) { dead = 1; return; }
            if (guard > 60000) { atomicExch(&g_abort, 1); dead = 1; return; }
        }
    }
    pc = v;
}

// hx layout (LDS, f16): hxT[col=batch 0..63][k 0..255], k<120 = own h(t-1),
// k=120..239 = below h(t) (l>0) or k=120 = x(t) (l=0), rest zero-padded.
// GEMM: gates[480p x 64] = Wp[480p x K] * hx[K x 64], rows permuted
// r' = cell*4 + gate.
__global__ __launch_bounds__(THR, 2) void lstm_kernel(
    const float* __restrict__ x,    const float* __restrict__ h0,
    const float* __restrict__ c0,   const float* __restrict__ Wih0,
    const float* __restrict__ Wih,  const float* __restrict__ Whh,
    const float* __restrict__ bih,  const float* __restrict__ bhh,
    const float* __restrict__ Wlin, const float* __restrict__ blin,
    float* __restrict__ out)
{
    __shared__ _Float16 hxT[64 * KPh];   // 33.8 KB

    const int bx   = blockIdx.x;
    const int l    = bx >> 2;
    const int bc   = bx & 3;
    const int tid  = threadIdx.x;
    const int w    = tid >> 6;
    const int lane = tid & 63;
    const int quad = lane >> 4;
    const int l16  = lane & 15;
    const int bg0  = bc * 64;
    const int KTl  = (l == 0) ? 4 : 8;
    const int mtn  = (w < 6) ? 4 : 3;           // m-tiles this wave
    const int mt0  = (w < 6) ? 4 * w : 24 + 3 * (w - 6);
    int dead = 0, pcb = -0x40000000, pca = -0x40000000;

    const float* WhhL = Whh + (size_t)l * 4 * Hn * Hn;
    const float* WihL = (l > 0) ? Wih + (size_t)(l - 1) * 4 * Hn * Hn : Whh;
    ushort_t* ringP = g_ring + (size_t)l * Dd * NBC * 64 * Hn;          // l<3
    const ushort_t* ringC =
        g_ring + (size_t)(l > 0 ? l - 1 : 0) * Dd * NBC * 64 * Hn;

    // ---- persistent A-fragments (weights, f16) in VGPRs.
    // A[m=lane&15][k=quad*8+j]; permuted row r' -> orig row gate*Hn+cell.
    f16x8 a[4][8];
    #pragma unroll
    for (int m = 0; m < 4; ++m) {
        int rp = (mt0 + m) * 16 + l16;          // permuted row 0..479
        int cell = rp >> 2, gate = rp & 3;
        int orow = gate * Hn + cell;
        for (int kt = 0; kt < 8; ++kt) {
            f16x8 av;
            #pragma unroll
            for (int j = 0; j < 8; ++j) {
                int k = kt * 32 + quad * 8 + j;
                float v = 0.f;
                if (m < mtn) {
                    if (k < Hn)            v = WhhL[orow * Hn + k];
                    else if (l == 0)       v = (k == Hn) ? Wih0[orow] : 0.f;
                    else if (k < 2 * Hn)   v = WihL[orow * Hn + (k - Hn)];
                }
                av[j] = (_Float16)v;
            }
            a[m][kt] = av;
        }
    }

    // bias per (m, gate); c-state per (m, n)
    float bias_g[4][4];
    float cst[4][4];
    #pragma unroll
    for (int m = 0; m < 4; ++m) {
        int cell = (mt0 + m) * 4 + quad;
        #pragma unroll
        for (int g = 0; g < 4; ++g)
            bias_g[m][g] = (m < mtn)
                ? bih[l * 4 * Hn + g * Hn + cell] + bhh[l * 4 * Hn + g * Hn + cell]
                : 0.f;
        #pragma unroll
        for (int n = 0; n < 4; ++n) {
            int col = n * 16 + l16;
            cst[m][n] = (m < mtn) ? c0[(l * Bn + bg0 + col) * Hn + cell] : 0.f;
        }
    }

    // producer copy indices (l<3): 960 dwordx4 = 64 cols x 15 groups of 8
    const int cp0_c = tid / 15,         cp0_g = tid % 15;
    const int cp1_c = (tid + 512) / 15, cp1_g = (tid + 512) % 15;

    // l3 output: 8 threads per col, W_lin slice hoisted to registers
    const int oc_col = tid >> 3, oc_j = tid & 7;
    float wl[15];
    if (l == 3) {
        #pragma unroll
        for (int c2 = 0; c2 < 15; ++c2) wl[c2] = Wlin[oc_j * 15 + c2];
    }

    // hxT init: own h from h0; zero k in [120,256)
    for (int q = tid; q < 64 * Hn; q += THR) {
        int col = q / Hn, cell = q % Hn;
        hxT[col * KPh + cell] = (_Float16)h0[(l * Bn + bg0 + col) * Hn + cell];
    }
    for (int q = tid; q < 64 * 136; q += THR) {
        int col = q / 136, kk = 120 + q % 136;
        hxT[col * KPh + kk] = (_Float16)0.f;
    }
    __syncthreads();

    for (int t = 0; t < Tn; ++t) {
        const int slot = t & (Dd - 1);

        if (l > 0 && tid == 0)
            spin_wait(&g_prod[((l - 1) * NBC + bc) * PADI], t, dead, pcb);
        if (l < 3 && t >= Dd && tid == 64)
            spin_wait(&g_cons[((l + 1) * NBC + bc) * PADI], t - Dd, dead, pca);
        __syncthreads();

        // ---- stage below-h (l>0) into hxT[.][120..240), raw f16 bits
        if (l > 0) {
            u32x4 v0 = {0,0,0,0}, v1 = {0,0,0,0};
            int q0 = tid, q1 = tid + THR;       // 960 dwordx4 total
            const ushort_t* base = ringC + ((size_t)(slot * NBC + bc)) * 64 * Hn;
            if (q0 < 960) {
                const ushort_t* p = base + (q0 / 15) * Hn + (q0 % 15) * 8;
                asm volatile("global_load_dwordx4 %0, %1, off sc0 sc1"
                             : "=v"(v0) : "v"(p));
            }
            if (q1 < 960) {
                const ushort_t* p = base + (q1 / 15) * Hn + (q1 % 15) * 8;
                asm volatile("global_load_dwordx4 %0, %1, off sc0 sc1"
                             : "=v"(v1) : "v"(p));
            }
            asm volatile("s_waitcnt vmcnt(0)" ::: "memory");
            if (q0 < 960)
                *(u32x4*)&hxT[(q0 / 15) * KPh + 120 + (q0 % 15) * 8] = v0;
            if (q1 < 960)
                *(u32x4*)&hxT[(q1 / 15) * KPh + 120 + (q1 % 15) * 8] = v1;
        } else {
            if (tid < 64) hxT[tid * KPh + 120] = (_Float16)x[t * Bn + bg0 + tid];
        }
        __syncthreads();
        if (l > 0 && tid == 96)
            atomicExch(&g_cons[(l * NBC + bc) * PADI], t);   // staged thru t

        // ---- MFMA: acc[m][n] (+= bias)
        f32x4 acc[4][4];
        #pragma unroll
        for (int m = 0; m < 4; ++m)
            #pragma unroll
            for (int n = 0; n < 4; ++n) {
                f32x4 z; z[0] = bias_g[m][0]; z[1] = bias_g[m][1];
                z[2] = bias_g[m][2]; z[3] = bias_g[m][3];
                acc[m][n] = z;
            }
        for (int kt = 0; kt < KTl; ++kt) {
            f16x8 bfr[4];
            #pragma unroll
            for (int n = 0; n < 4; ++n)
                bfr[n] = *(const f16x8*)&hxT[(n * 16 + l16) * KPh + kt * 32 + quad * 8];
            #pragma unroll
            for (int m = 0; m < 4; ++m)
                if (m < mtn)
                    #pragma unroll
                    for (int n = 0; n < 4; ++n)
                        acc[m][n] = __builtin_amdgcn_mfma_f32_16x16x32_f16(
                            a[m][kt], bfr[n], acc[m][n], 0, 0, 0);
        }
        __syncthreads();   // all B reads done before h(t) overwrites hxT

        // ---- in-register cell update; lane owns (cell=(mt0+m)*4+quad, col)
        #pragma unroll
        for (int m = 0; m < 4; ++m) {
            if (m >= mtn) continue;
            #pragma unroll
            for (int n = 0; n < 4; ++n) {
                int col = n * 16 + l16;
                int cell = (mt0 + m) * 4 + quad;
                float ig = sigm(acc[m][n][0]);
                float fg = sigm(acc[m][n][1]);
                float gg = tanh_fast(acc[m][n][2]);
                float og = sigm(acc[m][n][3]);
                float cn = fmaf(fg, cst[m][n], ig * gg);
                cst[m][n] = cn;
                float hn = og * tanh_fast(cn);
                hxT[col * KPh + cell] = (_Float16)hn;
            }
        }
        __syncthreads();   // h(t) complete in hxT

        if (l < 3) {
            // ---- coalesced hxT -> ring copy, 960 dwordx4 (2 per thread)
            ushort_t* rp = ringP + (size_t)(slot * NBC + bc) * 64 * Hn;
            {
                u32x4 v0 = *(const u32x4*)&hxT[cp0_c * KPh + cp0_g * 8];
                ushort_t* p0 = rp + cp0_c * Hn + cp0_g * 8;
                asm volatile("global_store_dwordx4 %0, %1, off sc0 sc1"
                             :: "v"(p0), "v"(v0) : "memory");
            }
            if (tid + 512 < 960) {
                u32x4 v1 = *(const u32x4*)&hxT[cp1_c * KPh + cp1_g * 8];
                ushort_t* p1 = rp + cp1_c * Hn + cp1_g * 8;
                asm volatile("global_store_dwordx4 %0, %1, off sc0 sc1"
                             :: "v"(p1), "v"(v1) : "memory");
            }
            asm volatile("s_waitcnt vmcnt(0)" ::: "memory");  // ring at MALL
            __syncthreads();
            if (tid == 0) atomicExch(&g_prod[(l * NBC + bc) * PADI], t);
        } else {
            // ---- out = W_lin . h3 + b_lin, 8 threads/col, shfl reduce
            float pout = 0.f;
            const _Float16* hrow = &hxT[oc_col * KPh + oc_j * 15];
            #pragma unroll
            for (int c2 = 0; c2 < 15; ++c2)
                pout = fmaf(wl[c2], (float)hrow[c2], pout);
            pout += __shfl_down(pout, 4, 8);
            pout += __shfl_down(pout, 2, 8);
            pout += __shfl_down(pout, 1, 8);
            if (oc_j == 0) out[t * Bn + bg0 + oc_col] = pout + blin[0];
        }
    }
}

extern "C" void kernel_launch(void* const* d_in, const int* in_sizes, int n_in,
                              void* d_out, int out_size, void* d_ws, size_t ws_size,
                              hipStream_t stream) {
    const float* x    = (const float*)d_in[0];
    const float* h0   = (const float*)d_in[1];
    const float* c0   = (const float*)d_in[2];
    const float* Wih0 = (const float*)d_in[3];
    const float* Wih  = (const float*)d_in[4];
    const float* Whh  = (const float*)d_in[5];
    const float* bih  = (const float*)d_in[6];
    const float* bhh  = (const float*)d_in[7];
    const float* Wlin = (const float*)d_in[8];
    const float* blin = (const float*)d_in[9];
    float* out = (float*)d_out;

    hipLaunchKernelGGL(init_kernel, dim3(1), dim3(256), 0, stream);
    hipLaunchKernelGGL(lstm_kernel, dim3(NBLK), dim3(THR), 0, stream,
                       x, h0, c0, Wih0, Wih, Whh, bih, bhh, Wlin, blin, out);
}

// Round 4
// 9221.793 us; speedup vs baseline: 1.5548x; 1.1250x over previous
//
#include <hip/hip_runtime.h>
#include <hip/hip_fp16.h>
#include <math.h>

#define Tn 1024
#define Bn 256
#define Hn 120
#define Ln 4
#define NBC 8                 // batch chunks of 32
#define NBCOL 32              // cols per chunk
#define NBLK (Ln*NBC)         // 32 blocks, one per (layer, bc)
#define THR 512               // 8 waves
#define Dd 8                  // ring depth
#define PADI 32
#define KPh 264               // hxT half-stride (16B-aligned rows)

typedef _Float16 f16x8 __attribute__((ext_vector_type(8)));
typedef float    f32x4 __attribute__((ext_vector_type(4)));
typedef unsigned int u32x4 __attribute__((ext_vector_type(4)));
typedef unsigned short ushort_t;

// R17 (resubmit; prior run was a container infra failure, kernel unbenched):
// R16b with NBC 4 -> 8 (32-col batch chunks, 32 blocks / 32 CUs).
// Batch chunks are fully independent pipelines; halving per-block work
// halves every scaling term of the serial per-step body (stage loads,
// MFMA count, B-frag ds_reads, cell-update transcendentals) while the
// fixed latency terms (2x vmcnt(0) drain, 5 barriers, flag posts) stay.
__device__ ushort_t g_ring[(size_t)3 * Dd * NBC * NBCOL * Hn]; // [l][slot][bc][b][cell]
__device__ int g_prod[3 * NBC * PADI];
__device__ int g_cons[Ln * NBC * PADI];
__device__ int g_abort;

__global__ __launch_bounds__(256) void init_kernel() {
    int idx = threadIdx.x;
    if (idx < 3 * NBC)  g_prod[idx * PADI] = -1;
    if (idx < Ln * NBC) g_cons[idx * PADI] = -1;
    if (idx == 0)       g_abort = 0;
}

#if __has_builtin(__builtin_amdgcn_exp2f)
__device__ __forceinline__ float hw_exp2(float x) { return __builtin_amdgcn_exp2f(x); }
#else
__device__ __forceinline__ float hw_exp2(float x) { return exp2f(x); }
#endif
#if __has_builtin(__builtin_amdgcn_rcpf)
__device__ __forceinline__ float hw_rcp(float x) { return __builtin_amdgcn_rcpf(x); }
#else
__device__ __forceinline__ float hw_rcp(float x) { return 1.0f / x; }
#endif
#define LOG2E_F 1.44269504f

__device__ __forceinline__ float sigm(float v) {
    return hw_rcp(1.0f + hw_exp2(-LOG2E_F * v));
}
__device__ __forceinline__ float tanh_fast(float v) {
    // tanh(x) = 1 - 2/(exp2(2x*log2e)+1); exact at +-inf, 0 at 0
    return 1.0f - 2.0f * hw_rcp(1.0f + hw_exp2(2.0f * LOG2E_F * v));
}

__device__ __forceinline__ void spin_wait(int* p, int tgt, int& dead, int& pc) {
    if (dead || pc >= tgt) return;
    int guard = 0, v;
    while ((v = __hip_atomic_load(p, __ATOMIC_RELAXED,
                                  __HIP_MEMORY_SCOPE_SYSTEM)) < tgt) {
        __builtin_amdgcn_s_sleep(1);
        if ((++guard & 127) == 0) {
            if (__hip_atomic_load(&g_abort, __ATOMIC_RELAXED,
                                  __HIP_MEMORY_SCOPE_SYSTEM)) { dead = 1; return; }
            if (guard > 60000) { atomicExch(&g_abort, 1); dead = 1; return; }
        }
    }
    pc = v;
}

// hx layout (LDS, f16): hxT[col=batch 0..31][k 0..255], k<120 = own h(t-1),
// k=120..239 = below h(t) (l>0) or k=120 = x(t) (l=0), rest zero-padded.
// GEMM: gates[480p x 32] = Wp[480p x K] * hx[K x 32], rows permuted
// r' = cell*4 + gate.
__global__ __launch_bounds__(THR, 2) void lstm_kernel(
    const float* __restrict__ x,    const float* __restrict__ h0,
    const float* __restrict__ c0,   const float* __restrict__ Wih0,
    const float* __restrict__ Wih,  const float* __restrict__ Whh,
    const float* __restrict__ bih,  const float* __restrict__ bhh,
    const float* __restrict__ Wlin, const float* __restrict__ blin,
    float* __restrict__ out)
{
    __shared__ _Float16 hxT[NBCOL * KPh];   // 16.9 KB

    const int bx   = blockIdx.x;
    const int l    = bx >> 3;
    const int bc   = bx & 7;
    const int tid  = threadIdx.x;
    const int w    = tid >> 6;
    const int lane = tid & 63;
    const int quad = lane >> 4;
    const int l16  = lane & 15;
    const int bg0  = bc * NBCOL;
    const int KTl  = (l == 0) ? 4 : 8;
    const int mtn  = (w < 6) ? 4 : 3;           // m-tiles this wave
    const int mt0  = (w < 6) ? 4 * w : 24 + 3 * (w - 6);
    int dead = 0, pcb = -0x40000000, pca = -0x40000000;

    const float* WhhL = Whh + (size_t)l * 4 * Hn * Hn;
    const float* WihL = (l > 0) ? Wih + (size_t)(l - 1) * 4 * Hn * Hn : Whh;
    ushort_t* ringP = g_ring + (size_t)l * Dd * NBC * NBCOL * Hn;       // l<3
    const ushort_t* ringC =
        g_ring + (size_t)(l > 0 ? l - 1 : 0) * Dd * NBC * NBCOL * Hn;

    // ---- persistent A-fragments (weights, f16) in VGPRs.
    // A[m=lane&15][k=quad*8+j]; permuted row r' -> orig row gate*Hn+cell.
    f16x8 a[4][8];
    #pragma unroll
    for (int m = 0; m < 4; ++m) {
        int rp = (mt0 + m) * 16 + l16;          // permuted row 0..479
        int cell = rp >> 2, gate = rp & 3;
        int orow = gate * Hn + cell;
        for (int kt = 0; kt < 8; ++kt) {
            f16x8 av;
            #pragma unroll
            for (int j = 0; j < 8; ++j) {
                int k = kt * 32 + quad * 8 + j;
                float v = 0.f;
                if (m < mtn) {
                    if (k < Hn)            v = WhhL[orow * Hn + k];
                    else if (l == 0)       v = (k == Hn) ? Wih0[orow] : 0.f;
                    else if (k < 2 * Hn)   v = WihL[orow * Hn + (k - Hn)];
                }
                av[j] = (_Float16)v;
            }
            a[m][kt] = av;
        }
    }

    // bias per (m, gate); c-state per (m, n)
    float bias_g[4][4];
    float cst[4][2];
    #pragma unroll
    for (int m = 0; m < 4; ++m) {
        int cell = (mt0 + m) * 4 + quad;
        #pragma unroll
        for (int g = 0; g < 4; ++g)
            bias_g[m][g] = (m < mtn)
                ? bih[l * 4 * Hn + g * Hn + cell] + bhh[l * 4 * Hn + g * Hn + cell]
                : 0.f;
        #pragma unroll
        for (int n = 0; n < 2; ++n) {
            int col = n * 16 + l16;
            cst[m][n] = (m < mtn) ? c0[(l * Bn + bg0 + col) * Hn + cell] : 0.f;
        }
    }

    // copy indices: 480 dwordx4 = 32 cols x 15 groups of 8 halves
    const int cp_c = tid / 15, cp_g = tid % 15;   // valid for tid<480

    // l3 output: 8 threads per col, W_lin slice hoisted to registers
    const int oc_col = tid >> 3, oc_j = tid & 7;  // valid for tid<256
    float wl[15];
    if (l == 3) {
        #pragma unroll
        for (int c2 = 0; c2 < 15; ++c2) wl[c2] = Wlin[oc_j * 15 + c2];
    }

    // hxT init: own h from h0; zero k in [120,256)
    for (int q = tid; q < NBCOL * Hn; q += THR) {
        int col = q / Hn, cell = q % Hn;
        hxT[col * KPh + cell] = (_Float16)h0[(l * Bn + bg0 + col) * Hn + cell];
    }
    for (int q = tid; q < NBCOL * 136; q += THR) {
        int col = q / 136, kk = 120 + q % 136;
        hxT[col * KPh + kk] = (_Float16)0.f;
    }
    __syncthreads();

    for (int t = 0; t < Tn; ++t) {
        const int slot = t & (Dd - 1);

        if (l > 0 && tid == 0)
            spin_wait(&g_prod[((l - 1) * NBC + bc) * PADI], t, dead, pcb);
        if (l < 3 && t >= Dd && tid == 64)
            spin_wait(&g_cons[((l + 1) * NBC + bc) * PADI], t - Dd, dead, pca);
        __syncthreads();

        // ---- stage below-h (l>0) into hxT[.][120..240), raw f16 bits
        if (l > 0) {
            u32x4 v0 = {0,0,0,0};
            const ushort_t* base = ringC + ((size_t)(slot * NBC + bc)) * NBCOL * Hn;
            if (tid < 480) {
                const ushort_t* p = base + cp_c * Hn + cp_g * 8;
                asm volatile("global_load_dwordx4 %0, %1, off sc0 sc1"
                             : "=v"(v0) : "v"(p));
            }
            asm volatile("s_waitcnt vmcnt(0)" ::: "memory");
            if (tid < 480)
                *(u32x4*)&hxT[cp_c * KPh + 120 + cp_g * 8] = v0;
        } else {
            if (tid < NBCOL) hxT[tid * KPh + 120] = (_Float16)x[t * Bn + bg0 + tid];
        }
        __syncthreads();
        if (l > 0 && tid == 96)
            atomicExch(&g_cons[(l * NBC + bc) * PADI], t);   // staged thru t

        // ---- MFMA: acc[m][n] (+= bias)
        f32x4 acc[4][2];
        #pragma unroll
        for (int m = 0; m < 4; ++m)
            #pragma unroll
            for (int n = 0; n < 2; ++n) {
                f32x4 z; z[0] = bias_g[m][0]; z[1] = bias_g[m][1];
                z[2] = bias_g[m][2]; z[3] = bias_g[m][3];
                acc[m][n] = z;
            }
        for (int kt = 0; kt < KTl; ++kt) {
            f16x8 bfr[2];
            #pragma unroll
            for (int n = 0; n < 2; ++n)
                bfr[n] = *(const f16x8*)&hxT[(n * 16 + l16) * KPh + kt * 32 + quad * 8];
            #pragma unroll
            for (int m = 0; m < 4; ++m)
                if (m < mtn)
                    #pragma unroll
                    for (int n = 0; n < 2; ++n)
                        acc[m][n] = __builtin_amdgcn_mfma_f32_16x16x32_f16(
                            a[m][kt], bfr[n], acc[m][n], 0, 0, 0);
        }
        __syncthreads();   // all B reads done before h(t) overwrites hxT

        // ---- in-register cell update; lane owns (cell=(mt0+m)*4+quad, col)
        #pragma unroll
        for (int m = 0; m < 4; ++m) {
            if (m >= mtn) continue;
            #pragma unroll
            for (int n = 0; n < 2; ++n) {
                int col = n * 16 + l16;
                int cell = (mt0 + m) * 4 + quad;
                float ig = sigm(acc[m][n][0]);
                float fg = sigm(acc[m][n][1]);
                float gg = tanh_fast(acc[m][n][2]);
                float og = sigm(acc[m][n][3]);
                float cn = fmaf(fg, cst[m][n], ig * gg);
                cst[m][n] = cn;
                float hn = og * tanh_fast(cn);
                hxT[col * KPh + cell] = (_Float16)hn;
            }
        }
        __syncthreads();   // h(t) complete in hxT

        if (l < 3) {
            // ---- coalesced hxT -> ring copy, 480 dwordx4 (1 per thread)
            ushort_t* rp = ringP + (size_t)(slot * NBC + bc) * NBCOL * Hn;
            if (tid < 480) {
                u32x4 v0 = *(const u32x4*)&hxT[cp_c * KPh + cp_g * 8];
                ushort_t* p0 = rp + cp_c * Hn + cp_g * 8;
                asm volatile("global_store_dwordx4 %0, %1, off sc0 sc1"
                             :: "v"(p0), "v"(v0) : "memory");
            }
            asm volatile("s_waitcnt vmcnt(0)" ::: "memory");  // ring at MALL
            __syncthreads();
            if (tid == 0) atomicExch(&g_prod[(l * NBC + bc) * PADI], t);
        } else {
            // ---- out = W_lin . h3 + b_lin, 8 threads/col, shfl reduce
            if (tid < NBCOL * 8) {
                float pout = 0.f;
                const _Float16* hrow = &hxT[oc_col * KPh + oc_j * 15];
                #pragma unroll
                for (int c2 = 0; c2 < 15; ++c2)
                    pout = fmaf(wl[c2], (float)hrow[c2], pout);
                pout += __shfl_down(pout, 4, 8);
                pout += __shfl_down(pout, 2, 8);
                pout += __shfl_down(pout, 1, 8);
                if (oc_j == 0) out[t * Bn + bg0 + oc_col] = pout + blin[0];
            }
        }
    }
}

extern "C" void kernel_launch(void* const* d_in, const int* in_sizes, int n_in,
                              void* d_out, int out_size, void* d_ws, size_t ws_size,
                              hipStream_t stream) {
    const float* x    = (const float*)d_in[0];
    const float* h0   = (const float*)d_in[1];
    const float* c0   = (const float*)d_in[2];
    const float* Wih0 = (const float*)d_in[3];
    const float* Wih  = (const float*)d_in[4];
    const float* Whh  = (const float*)d_in[5];
    const float* bih  = (const float*)d_in[6];
    const float* bhh  = (const float*)d_in[7];
    const float* Wlin = (const float*)d_in[8];
    const float* blin = (const float*)d_in[9];
    float* out = (float*)d_out;

    hipLaunchKernelGGL(init_kernel, dim3(1), dim3(256), 0, stream);
    hipLaunchKernelGGL(lstm_kernel, dim3(NBLK), dim3(THR), 0, stream,
                       x, h0, c0, Wih0, Wih, Whh, bih, bhh, Wlin, blin, out);
}

// Round 5
// 8750.574 us; speedup vs baseline: 1.6385x; 1.0539x over previous
//
#include <hip/hip_runtime.h>
#include <hip/hip_fp16.h>
#include <math.h>

#define Tn 1024
#define Bn 256
#define Hn 120
#define Ln 4
#define NBC 8                 // batch chunks of 32
#define NBCOL 32              // cols per chunk
#define NBLK (Ln*NBC)         // 32 blocks, one per (layer, bc)
#define THR 512               // 8 waves
#define Dd 8                  // ring depth
#define PADI 32
#define KPh 264               // hxT half-stride (16B-aligned rows)

typedef _Float16 f16x8 __attribute__((ext_vector_type(8)));
typedef float    f32x4 __attribute__((ext_vector_type(4)));
typedef unsigned int u32x4 __attribute__((ext_vector_type(4)));
typedef unsigned short ushort_t;

// R18: latency-restructured body. Steady-state rate = per-step body time
// (hop latency only shifts layer offsets; ring depth 8 gives slack), so:
// (1) prefetch below-h(t+1) in the same vmem phase as the h(t) ring
//     stores, ONE combined vmcnt(0) drain (was 2 sequential round trips),
// (2) spin checks at step entry (targets t+1 / t-8), overlapped with the
//     other waves' GEMM; pc-caching skips most polls,
// (3) barriers 5 -> 3 per step; flag posts after the last barrier so
//     their system-scope completion hides under the next GEMM.
// cons(t) semantic now = "loads for bh(t) drained" (posted after the
// combined drain) -- exactly the producer's depth-8 overwrite guard.
__device__ ushort_t g_ring[(size_t)3 * Dd * NBC * NBCOL * Hn]; // [l][slot][bc][b][cell]
__device__ int g_prod[3 * NBC * PADI];
__device__ int g_cons[Ln * NBC * PADI];
__device__ int g_abort;

__global__ __launch_bounds__(256) void init_kernel() {
    int idx = threadIdx.x;
    if (idx < 3 * NBC)  g_prod[idx * PADI] = -1;
    if (idx < Ln * NBC) g_cons[idx * PADI] = -1;
    if (idx == 0)       g_abort = 0;
}

#if __has_builtin(__builtin_amdgcn_exp2f)
__device__ __forceinline__ float hw_exp2(float x) { return __builtin_amdgcn_exp2f(x); }
#else
__device__ __forceinline__ float hw_exp2(float x) { return exp2f(x); }
#endif
#if __has_builtin(__builtin_amdgcn_rcpf)
__device__ __forceinline__ float hw_rcp(float x) { return __builtin_amdgcn_rcpf(x); }
#else
__device__ __forceinline__ float hw_rcp(float x) { return 1.0f / x; }
#endif
#define LOG2E_F 1.44269504f

__device__ __forceinline__ float sigm(float v) {
    return hw_rcp(1.0f + hw_exp2(-LOG2E_F * v));
}
__device__ __forceinline__ float tanh_fast(float v) {
    // tanh(x) = 1 - 2/(exp2(2x*log2e)+1); exact at +-inf, 0 at 0
    return 1.0f - 2.0f * hw_rcp(1.0f + hw_exp2(2.0f * LOG2E_F * v));
}

__device__ __forceinline__ void spin_wait(int* p, int tgt, int& dead, int& pc) {
    if (dead || pc >= tgt) return;
    int guard = 0, v;
    while ((v = __hip_atomic_load(p, __ATOMIC_RELAXED,
                                  __HIP_MEMORY_SCOPE_SYSTEM)) < tgt) {
        __builtin_amdgcn_s_sleep(1);
        if ((++guard & 127) == 0) {
            if (__hip_atomic_load(&g_abort, __ATOMIC_RELAXED,
                                  __HIP_MEMORY_SCOPE_SYSTEM)) { dead = 1; return; }
            if (guard > 60000) { atomicExch(&g_abort, 1); dead = 1; return; }
        }
    }
    pc = v;
}

// hx layout (LDS, f16): hxT[col=batch 0..31][k 0..255], k<120 = own h(t-1),
// k=120..239 = below h(t) (l>0) or k=120 = x(t) (l=0), rest zero-padded.
// GEMM: gates[480p x 32] = Wp[480p x K] * hx[K x 32], rows permuted
// r' = cell*4 + gate.
__global__ __launch_bounds__(THR, 2) void lstm_kernel(
    const float* __restrict__ x,    const float* __restrict__ h0,
    const float* __restrict__ c0,   const float* __restrict__ Wih0,
    const float* __restrict__ Wih,  const float* __restrict__ Whh,
    const float* __restrict__ bih,  const float* __restrict__ bhh,
    const float* __restrict__ Wlin, const float* __restrict__ blin,
    float* __restrict__ out)
{
    __shared__ _Float16 hxT[NBCOL * KPh];   // 16.9 KB

    const int bx   = blockIdx.x;
    const int l    = bx >> 3;
    const int bc   = bx & 7;
    const int tid  = threadIdx.x;
    const int w    = tid >> 6;
    const int lane = tid & 63;
    const int quad = lane >> 4;
    const int l16  = lane & 15;
    const int bg0  = bc * NBCOL;
    const int KTl  = (l == 0) ? 4 : 8;
    const int mtn  = (w < 6) ? 4 : 3;           // m-tiles this wave
    const int mt0  = (w < 6) ? 4 * w : 24 + 3 * (w - 6);
    int dead = 0, pcb = -0x40000000, pca = -0x40000000;

    const float* WhhL = Whh + (size_t)l * 4 * Hn * Hn;
    const float* WihL = (l > 0) ? Wih + (size_t)(l - 1) * 4 * Hn * Hn : Whh;
    ushort_t* ringP = g_ring + (size_t)l * Dd * NBC * NBCOL * Hn;       // l<3
    const ushort_t* ringC =
        g_ring + (size_t)(l > 0 ? l - 1 : 0) * Dd * NBC * NBCOL * Hn;

    // ---- persistent A-fragments (weights, f16) in VGPRs.
    // A[m=lane&15][k=quad*8+j]; permuted row r' -> orig row gate*Hn+cell.
    f16x8 a[4][8];
    #pragma unroll
    for (int m = 0; m < 4; ++m) {
        int rp = (mt0 + m) * 16 + l16;          // permuted row 0..479
        int cell = rp >> 2, gate = rp & 3;
        int orow = gate * Hn + cell;
        for (int kt = 0; kt < 8; ++kt) {
            f16x8 av;
            #pragma unroll
            for (int j = 0; j < 8; ++j) {
                int k = kt * 32 + quad * 8 + j;
                float v = 0.f;
                if (m < mtn) {
                    if (k < Hn)            v = WhhL[orow * Hn + k];
                    else if (l == 0)       v = (k == Hn) ? Wih0[orow] : 0.f;
                    else if (k < 2 * Hn)   v = WihL[orow * Hn + (k - Hn)];
                }
                av[j] = (_Float16)v;
            }
            a[m][kt] = av;
        }
    }

    // bias per (m, gate); c-state per (m, n)
    float bias_g[4][4];
    float cst[4][2];
    #pragma unroll
    for (int m = 0; m < 4; ++m) {
        int cell = (mt0 + m) * 4 + quad;
        #pragma unroll
        for (int g = 0; g < 4; ++g)
            bias_g[m][g] = (m < mtn)
                ? bih[l * 4 * Hn + g * Hn + cell] + bhh[l * 4 * Hn + g * Hn + cell]
                : 0.f;
        #pragma unroll
        for (int n = 0; n < 2; ++n) {
            int col = n * 16 + l16;
            cst[m][n] = (m < mtn) ? c0[(l * Bn + bg0 + col) * Hn + cell] : 0.f;
        }
    }

    // copy indices: 480 dwordx4 = 32 cols x 15 groups of 8 halves
    const int cp_c = tid / 15, cp_g = tid % 15;   // valid for tid<480

    // l3 output: 8 threads per col, W_lin slice hoisted to registers
    const int oc_col = tid >> 3, oc_j = tid & 7;  // valid for tid<256
    float wl[15];
    if (l == 3) {
        #pragma unroll
        for (int c2 = 0; c2 < 15; ++c2) wl[c2] = Wlin[oc_j * 15 + c2];
    }

    // hxT init: own h from h0; zero k in [120,256)
    for (int q = tid; q < NBCOL * Hn; q += THR) {
        int col = q / Hn, cell = q % Hn;
        hxT[col * KPh + cell] = (_Float16)h0[(l * Bn + bg0 + col) * Hn + cell];
    }
    for (int q = tid; q < NBCOL * 136; q += THR) {
        int col = q / 136, kk = 120 + q % 136;
        hxT[col * KPh + kk] = (_Float16)0.f;
    }
    __syncthreads();

    // ---- prologue: stage bh(0) (l>0) or x(0) (l=0)
    if (l > 0) {
        if (tid == 0)
            spin_wait(&g_prod[((l - 1) * NBC + bc) * PADI], 0, dead, pcb);
        __syncthreads();
        u32x4 v0 = {0,0,0,0};
        const ushort_t* base = ringC + ((size_t)(0 * NBC + bc)) * NBCOL * Hn;
        if (tid < 480) {
            const ushort_t* p = base + cp_c * Hn + cp_g * 8;
            asm volatile("global_load_dwordx4 %0, %1, off sc0 sc1"
                         : "=v"(v0) : "v"(p));
        }
        asm volatile("s_waitcnt vmcnt(0)" ::: "memory");
        if (tid < 480)
            *(u32x4*)&hxT[cp_c * KPh + 120 + cp_g * 8] = v0;
        __syncthreads();
        if (tid == 96)
            atomicExch(&g_cons[(l * NBC + bc) * PADI], 0);   // bh(0) drained
    } else {
        if (tid < NBCOL) hxT[tid * KPh + 120] = (_Float16)x[bg0 + tid];
        __syncthreads();
    }

    for (int t = 0; t < Tn; ++t) {
        const int slotW = t & (Dd - 1);           // store slot: h(t)
        const int slotR = (t + 1) & (Dd - 1);     // prefetch slot: bh(t+1)

        // ---- entry spins (cached; overlap other waves' GEMM)
        if (l > 0 && tid == 0 && (t + 1) < Tn)
            spin_wait(&g_prod[((l - 1) * NBC + bc) * PADI], t + 1, dead, pcb);
        if (l < 3 && tid == 64 && t >= Dd)
            spin_wait(&g_cons[((l + 1) * NBC + bc) * PADI], t - Dd, dead, pca);

        // ---- GEMM over full K (bh(t)/x(t) already in LDS)
        f32x4 acc[4][2];
        #pragma unroll
        for (int m = 0; m < 4; ++m)
            #pragma unroll
            for (int n = 0; n < 2; ++n) {
                f32x4 z; z[0] = bias_g[m][0]; z[1] = bias_g[m][1];
                z[2] = bias_g[m][2]; z[3] = bias_g[m][3];
                acc[m][n] = z;
            }
        for (int kt = 0; kt < KTl; ++kt) {
            f16x8 bfr[2];
            #pragma unroll
            for (int n = 0; n < 2; ++n)
                bfr[n] = *(const f16x8*)&hxT[(n * 16 + l16) * KPh + kt * 32 + quad * 8];
            #pragma unroll
            for (int m = 0; m < 4; ++m)
                if (m < mtn)
                    #pragma unroll
                    for (int n = 0; n < 2; ++n)
                        acc[m][n] = __builtin_amdgcn_mfma_f32_16x16x32_f16(
                            a[m][kt], bfr[n], acc[m][n], 0, 0, 0);
        }
        __syncthreads();   // A: all B-frag reads done before h(t) overwrite

        // ---- in-register cell update; lane owns (cell=(mt0+m)*4+quad, col)
        #pragma unroll
        for (int m = 0; m < 4; ++m) {
            if (m >= mtn) continue;
            #pragma unroll
            for (int n = 0; n < 2; ++n) {
                int col = n * 16 + l16;
                int cell = (mt0 + m) * 4 + quad;
                float ig = sigm(acc[m][n][0]);
                float fg = sigm(acc[m][n][1]);
                float gg = tanh_fast(acc[m][n][2]);
                float og = sigm(acc[m][n][3]);
                float cn = fmaf(fg, cst[m][n], ig * gg);
                cst[m][n] = cn;
                float hn = og * tanh_fast(cn);
                hxT[col * KPh + cell] = (_Float16)hn;
            }
        }
        __syncthreads();   // B: h(t) complete in hxT

        // ---- vmem phase: ring stores S(t) + prefetch loads L(t+1) + out
        u32x4 ld = {0, 0, 0, 0};
        float xr = 0.f;
        if (l < 3 && tid < 480) {
            u32x4 v0 = *(const u32x4*)&hxT[cp_c * KPh + cp_g * 8];
            ushort_t* p0 = ringP + (size_t)(slotW * NBC + bc) * NBCOL * Hn
                         + cp_c * Hn + cp_g * 8;
            asm volatile("global_store_dwordx4 %0, %1, off sc0 sc1"
                         :: "v"(p0), "v"(v0) : "memory");
        }
        if (l > 0 && (t + 1) < Tn && tid < 480) {
            const ushort_t* p = ringC + (size_t)(slotR * NBC + bc) * NBCOL * Hn
                              + cp_c * Hn + cp_g * 8;
            asm volatile("global_load_dwordx4 %0, %1, off sc0 sc1"
                         : "=v"(ld) : "v"(p));
        }
        if (l == 0 && (t + 1) < Tn && tid < NBCOL)
            xr = x[(t + 1) * Bn + bg0 + tid];
        if (l == 3 && tid < NBCOL * 8) {
            // out = W_lin . h3 + b_lin, 8 threads/col, shfl reduce
            float pout = 0.f;
            const _Float16* hrow = &hxT[oc_col * KPh + oc_j * 15];
            #pragma unroll
            for (int c2 = 0; c2 < 15; ++c2)
                pout = fmaf(wl[c2], (float)hrow[c2], pout);
            pout += __shfl_down(pout, 4, 8);
            pout += __shfl_down(pout, 2, 8);
            pout += __shfl_down(pout, 1, 8);
            if (oc_j == 0) out[t * Bn + bg0 + oc_col] = pout + blin[0];
        }

        asm volatile("s_waitcnt vmcnt(0)" ::: "memory");   // ONE combined drain

        // ---- stage prefetched data into LDS B region
        if (l > 0 && (t + 1) < Tn && tid < 480)
            *(u32x4*)&hxT[cp_c * KPh + 120 + cp_g * 8] = ld;
        if (l == 0 && (t + 1) < Tn && tid < NBCOL)
            hxT[tid * KPh + 120] = (_Float16)xr;
        __syncthreads();   // C: staged data visible for next GEMM

        // ---- posts after last barrier: completion hides under next GEMM
        if (l < 3 && tid == 0)
            atomicExch(&g_prod[(l * NBC + bc) * PADI], t);
        if (l > 0 && tid == 96)
            atomicExch(&g_cons[(l * NBC + bc) * PADI], t + 1);
    }
}

extern "C" void kernel_launch(void* const* d_in, const int* in_sizes, int n_in,
                              void* d_out, int out_size, void* d_ws, size_t ws_size,
                              hipStream_t stream) {
    const float* x    = (const float*)d_in[0];
    const float* h0   = (const float*)d_in[1];
    const float* c0   = (const float*)d_in[2];
    const float* Wih0 = (const float*)d_in[3];
    const float* Wih  = (const float*)d_in[4];
    const float* Whh  = (const float*)d_in[5];
    const float* bih  = (const float*)d_in[6];
    const float* bhh  = (const float*)d_in[7];
    const float* Wlin = (const float*)d_in[8];
    const float* blin = (const float*)d_in[9];
    float* out = (float*)d_out;

    hipLaunchKernelGGL(init_kernel, dim3(1), dim3(256), 0, stream);
    hipLaunchKernelGGL(lstm_kernel, dim3(NBLK), dim3(THR), 0, stream,
                       x, h0, c0, Wih0, Wih, Whh, bih, bhh, Wlin, blin, out);
}

// Round 6
// 2827.525 us; speedup vs baseline: 5.0709x; 3.0948x over previous
//
#include <hip/hip_runtime.h>
#include <hip/hip_fp16.h>
#include <math.h>

#define Tn 1024
#define Bn 256
#define Hn 120
#define Ln 4
#define NBC 8                 // batch chunks of 32
#define NBCOL 32              // cols per chunk
#define NBLK (Ln*NBC)         // 32 blocks, one per (layer, bc)
#define THR 512               // 8 waves
#define Dd 8                  // ring depth
#define PADI 32
#define KPh 264               // hxT half-stride (16B-aligned rows)

typedef _Float16 f16x8 __attribute__((ext_vector_type(8)));
typedef float    f32x4 __attribute__((ext_vector_type(4)));
typedef unsigned int u32x4 __attribute__((ext_vector_type(4)));
typedef unsigned short ushort_t;

template<int N> struct IC { static constexpr int value = N; };

// R19: R18 with the weight A-fragments made GENUINELY register-resident.
// Evidence they were not: VGPR_Count=60 (< the 128 the array needs) and
// FETCH_SIZE ~106 MB ~= per-step weight re-reads. Cause: GEMM kt-loop had
// RUNTIME bound KTl (4 or 6/8 by layer) -> a[m][kt] dynamically indexed
// -> whole array demoted to scratch/memory, reloaded+cvt'd every step,
// serialized into the MFMA chain (rule #20). Fix: t-loop in a lambda
// templated on constexpr KTL (IC<4> l=0, IC<8> l>0), all kt loops fully
// unrolled -> static indices -> VGPR-resident. Sync protocol unchanged.
__device__ ushort_t g_ring[(size_t)3 * Dd * NBC * NBCOL * Hn]; // [l][slot][bc][b][cell]
__device__ int g_prod[3 * NBC * PADI];
__device__ int g_cons[Ln * NBC * PADI];
__device__ int g_abort;

__global__ __launch_bounds__(256) void init_kernel() {
    int idx = threadIdx.x;
    if (idx < 3 * NBC)  g_prod[idx * PADI] = -1;
    if (idx < Ln * NBC) g_cons[idx * PADI] = -1;
    if (idx == 0)       g_abort = 0;
}

#if __has_builtin(__builtin_amdgcn_exp2f)
__device__ __forceinline__ float hw_exp2(float x) { return __builtin_amdgcn_exp2f(x); }
#else
__device__ __forceinline__ float hw_exp2(float x) { return exp2f(x); }
#endif
#if __has_builtin(__builtin_amdgcn_rcpf)
__device__ __forceinline__ float hw_rcp(float x) { return __builtin_amdgcn_rcpf(x); }
#else
__device__ __forceinline__ float hw_rcp(float x) { return 1.0f / x; }
#endif
#define LOG2E_F 1.44269504f

__device__ __forceinline__ float sigm(float v) {
    return hw_rcp(1.0f + hw_exp2(-LOG2E_F * v));
}
__device__ __forceinline__ float tanh_fast(float v) {
    // tanh(x) = 1 - 2/(exp2(2x*log2e)+1); exact at +-inf, 0 at 0
    return 1.0f - 2.0f * hw_rcp(1.0f + hw_exp2(2.0f * LOG2E_F * v));
}

__device__ __forceinline__ void spin_wait(int* p, int tgt, int& dead, int& pc) {
    if (dead || pc >= tgt) return;
    int guard = 0, v;
    while ((v = __hip_atomic_load(p, __ATOMIC_RELAXED,
                                  __HIP_MEMORY_SCOPE_SYSTEM)) < tgt) {
        __builtin_amdgcn_s_sleep(1);
        if ((++guard & 127) == 0) {
            if (__hip_atomic_load(&g_abort, __ATOMIC_RELAXED,
                                  __HIP_MEMORY_SCOPE_SYSTEM)) { dead = 1; return; }
            if (guard > 60000) { atomicExch(&g_abort, 1); dead = 1; return; }
        }
    }
    pc = v;
}

// hx layout (LDS, f16): hxT[col=batch 0..31][k 0..255], k<120 = own h(t-1),
// k=120..239 = below h(t) (l>0) or k=120 = x(t) (l=0), rest zero-padded.
// GEMM: gates[480p x 32] = Wp[480p x K] * hx[K x 32], rows permuted
// r' = cell*4 + gate.
__global__ __launch_bounds__(THR, 2) void lstm_kernel(
    const float* __restrict__ x,    const float* __restrict__ h0,
    const float* __restrict__ c0,   const float* __restrict__ Wih0,
    const float* __restrict__ Wih,  const float* __restrict__ Whh,
    const float* __restrict__ bih,  const float* __restrict__ bhh,
    const float* __restrict__ Wlin, const float* __restrict__ blin,
    float* __restrict__ out)
{
    __shared__ _Float16 hxT[NBCOL * KPh];   // 16.9 KB

    const int bx   = blockIdx.x;
    const int l    = bx >> 3;
    const int bc   = bx & 7;
    const int tid  = threadIdx.x;
    const int w    = tid >> 6;
    const int lane = tid & 63;
    const int quad = lane >> 4;
    const int l16  = lane & 15;
    const int bg0  = bc * NBCOL;
    const int mtn  = (w < 6) ? 4 : 3;           // m-tiles this wave
    const int mt0  = (w < 6) ? 4 * w : 24 + 3 * (w - 6);
    int dead = 0, pcb = -0x40000000, pca = -0x40000000;

    const float* WhhL = Whh + (size_t)l * 4 * Hn * Hn;
    const float* WihL = (l > 0) ? Wih + (size_t)(l - 1) * 4 * Hn * Hn : Whh;
    ushort_t* ringP = g_ring + (size_t)l * Dd * NBC * NBCOL * Hn;       // l<3
    const ushort_t* ringC =
        g_ring + (size_t)(l > 0 ? l - 1 : 0) * Dd * NBC * NBCOL * Hn;

    // ---- persistent A-fragments (weights, f16) in VGPRs.
    // A[m=lane&15][k=quad*8+j]; permuted row r' -> orig row gate*Hn+cell.
    f16x8 a[4][8];
    #pragma unroll
    for (int m = 0; m < 4; ++m) {
        int rp = (mt0 + m) * 16 + l16;          // permuted row 0..479
        int cell = rp >> 2, gate = rp & 3;
        int orow = gate * Hn + cell;
        #pragma unroll
        for (int kt = 0; kt < 8; ++kt) {
            f16x8 av;
            #pragma unroll
            for (int j = 0; j < 8; ++j) {
                int k = kt * 32 + quad * 8 + j;
                float v = 0.f;
                if (m < mtn) {
                    if (k < Hn)            v = WhhL[orow * Hn + k];
                    else if (l == 0)       v = (k == Hn) ? Wih0[orow] : 0.f;
                    else if (k < 2 * Hn)   v = WihL[orow * Hn + (k - Hn)];
                }
                av[j] = (_Float16)v;
            }
            a[m][kt] = av;
        }
    }

    // bias per (m, gate); c-state per (m, n)
    float bias_g[4][4];
    float cst[4][2];
    #pragma unroll
    for (int m = 0; m < 4; ++m) {
        int cell = (mt0 + m) * 4 + quad;
        #pragma unroll
        for (int g = 0; g < 4; ++g)
            bias_g[m][g] = (m < mtn)
                ? bih[l * 4 * Hn + g * Hn + cell] + bhh[l * 4 * Hn + g * Hn + cell]
                : 0.f;
        #pragma unroll
        for (int n = 0; n < 2; ++n) {
            int col = n * 16 + l16;
            cst[m][n] = (m < mtn) ? c0[(l * Bn + bg0 + col) * Hn + cell] : 0.f;
        }
    }

    // copy indices: 480 dwordx4 = 32 cols x 15 groups of 8 halves
    const int cp_c = tid / 15, cp_g = tid % 15;   // valid for tid<480

    // l3 output: 8 threads per col, W_lin slice hoisted to registers
    const int oc_col = tid >> 3, oc_j = tid & 7;  // valid for tid<256
    float wl[15];
    if (l == 3) {
        #pragma unroll
        for (int c2 = 0; c2 < 15; ++c2) wl[c2] = Wlin[oc_j * 15 + c2];
    }

    // hxT init: own h from h0; zero k in [120,256)
    for (int q = tid; q < NBCOL * Hn; q += THR) {
        int col = q / Hn, cell = q % Hn;
        hxT[col * KPh + cell] = (_Float16)h0[(l * Bn + bg0 + col) * Hn + cell];
    }
    for (int q = tid; q < NBCOL * 136; q += THR) {
        int col = q / 136, kk = 120 + q % 136;
        hxT[col * KPh + kk] = (_Float16)0.f;
    }
    __syncthreads();

    // ---- prologue: stage bh(0) (l>0) or x(0) (l=0)
    if (l > 0) {
        if (tid == 0)
            spin_wait(&g_prod[((l - 1) * NBC + bc) * PADI], 0, dead, pcb);
        __syncthreads();
        u32x4 v0 = {0,0,0,0};
        const ushort_t* base = ringC + ((size_t)(0 * NBC + bc)) * NBCOL * Hn;
        if (tid < 480) {
            const ushort_t* p = base + cp_c * Hn + cp_g * 8;
            asm volatile("global_load_dwordx4 %0, %1, off sc0 sc1"
                         : "=v"(v0) : "v"(p));
        }
        asm volatile("s_waitcnt vmcnt(0)" ::: "memory");
        if (tid < 480)
            *(u32x4*)&hxT[cp_c * KPh + 120 + cp_g * 8] = v0;
        __syncthreads();
        if (tid == 96)
            atomicExch(&g_cons[(l * NBC + bc) * PADI], 0);   // bh(0) drained
    } else {
        if (tid < NBCOL) hxT[tid * KPh + 120] = (_Float16)x[bg0 + tid];
        __syncthreads();
    }

    // ---- steady-state loop, templated on compile-time K-tile count so
    // a[m][kt] indexing is fully static (VGPR-resident weights).
    auto run = [&](auto ktlc) {
        constexpr int KTL = decltype(ktlc)::value;
        for (int t = 0; t < Tn; ++t) {
            const int slotW = t & (Dd - 1);           // store slot: h(t)
            const int slotR = (t + 1) & (Dd - 1);     // prefetch slot: bh(t+1)

            // ---- entry spins (cached; overlap other waves' GEMM)
            if (l > 0 && tid == 0 && (t + 1) < Tn)
                spin_wait(&g_prod[((l - 1) * NBC + bc) * PADI], t + 1, dead, pcb);
            if (l < 3 && tid == 64 && t >= Dd)
                spin_wait(&g_cons[((l + 1) * NBC + bc) * PADI], t - Dd, dead, pca);

            // ---- GEMM over full K (bh(t)/x(t) already in LDS)
            f32x4 acc[4][2];
            #pragma unroll
            for (int m = 0; m < 4; ++m)
                #pragma unroll
                for (int n = 0; n < 2; ++n) {
                    f32x4 z; z[0] = bias_g[m][0]; z[1] = bias_g[m][1];
                    z[2] = bias_g[m][2]; z[3] = bias_g[m][3];
                    acc[m][n] = z;
                }
            #pragma unroll
            for (int kt = 0; kt < KTL; ++kt) {
                f16x8 bfr[2];
                #pragma unroll
                for (int n = 0; n < 2; ++n)
                    bfr[n] = *(const f16x8*)&hxT[(n * 16 + l16) * KPh + kt * 32 + quad * 8];
                #pragma unroll
                for (int m = 0; m < 4; ++m)
                    if (m < mtn)
                        #pragma unroll
                        for (int n = 0; n < 2; ++n)
                            acc[m][n] = __builtin_amdgcn_mfma_f32_16x16x32_f16(
                                a[m][kt], bfr[n], acc[m][n], 0, 0, 0);
            }
            __syncthreads();   // A: all B-frag reads done before h(t) overwrite

            // ---- in-register cell update; lane owns (cell=(mt0+m)*4+quad, col)
            #pragma unroll
            for (int m = 0; m < 4; ++m) {
                if (m >= mtn) continue;
                #pragma unroll
                for (int n = 0; n < 2; ++n) {
                    int col = n * 16 + l16;
                    int cell = (mt0 + m) * 4 + quad;
                    float ig = sigm(acc[m][n][0]);
                    float fg = sigm(acc[m][n][1]);
                    float gg = tanh_fast(acc[m][n][2]);
                    float og = sigm(acc[m][n][3]);
                    float cn = fmaf(fg, cst[m][n], ig * gg);
                    cst[m][n] = cn;
                    float hn = og * tanh_fast(cn);
                    hxT[col * KPh + cell] = (_Float16)hn;
                }
            }
            __syncthreads();   // B: h(t) complete in hxT

            // ---- vmem phase: ring stores S(t) + prefetch loads L(t+1) + out
            u32x4 ld = {0, 0, 0, 0};
            float xr = 0.f;
            if (l < 3 && tid < 480) {
                u32x4 v0 = *(const u32x4*)&hxT[cp_c * KPh + cp_g * 8];
                ushort_t* p0 = ringP + (size_t)(slotW * NBC + bc) * NBCOL * Hn
                             + cp_c * Hn + cp_g * 8;
                asm volatile("global_store_dwordx4 %0, %1, off sc0 sc1"
                             :: "v"(p0), "v"(v0) : "memory");
            }
            if (l > 0 && (t + 1) < Tn && tid < 480) {
                const ushort_t* p = ringC + (size_t)(slotR * NBC + bc) * NBCOL * Hn
                                  + cp_c * Hn + cp_g * 8;
                asm volatile("global_load_dwordx4 %0, %1, off sc0 sc1"
                             : "=v"(ld) : "v"(p));
            }
            if (l == 0 && (t + 1) < Tn && tid < NBCOL)
                xr = x[(t + 1) * Bn + bg0 + tid];
            if (l == 3 && tid < NBCOL * 8) {
                // out = W_lin . h3 + b_lin, 8 threads/col, shfl reduce
                float pout = 0.f;
                const _Float16* hrow = &hxT[oc_col * KPh + oc_j * 15];
                #pragma unroll
                for (int c2 = 0; c2 < 15; ++c2)
                    pout = fmaf(wl[c2], (float)hrow[c2], pout);
                pout += __shfl_down(pout, 4, 8);
                pout += __shfl_down(pout, 2, 8);
                pout += __shfl_down(pout, 1, 8);
                if (oc_j == 0) out[t * Bn + bg0 + oc_col] = pout + blin[0];
            }

            asm volatile("s_waitcnt vmcnt(0)" ::: "memory");   // ONE combined drain

            // ---- stage prefetched data into LDS B region
            if (l > 0 && (t + 1) < Tn && tid < 480)
                *(u32x4*)&hxT[cp_c * KPh + 120 + cp_g * 8] = ld;
            if (l == 0 && (t + 1) < Tn && tid < NBCOL)
                hxT[tid * KPh + 120] = (_Float16)xr;
            __syncthreads();   // C: staged data visible for next GEMM

            // ---- posts after last barrier: completion hides under next GEMM
            if (l < 3 && tid == 0)
                atomicExch(&g_prod[(l * NBC + bc) * PADI], t);
            if (l > 0 && tid == 96)
                atomicExch(&g_cons[(l * NBC + bc) * PADI], t + 1);
        }
    };
    if (l == 0) run(IC<4>{});
    else        run(IC<8>{});
}

extern "C" void kernel_launch(void* const* d_in, const int* in_sizes, int n_in,
                              void* d_out, int out_size, void* d_ws, size_t ws_size,
                              hipStream_t stream) {
    const float* x    = (const float*)d_in[0];
    const float* h0   = (const float*)d_in[1];
    const float* c0   = (const float*)d_in[2];
    const float* Wih0 = (const float*)d_in[3];
    const float* Wih  = (const float*)d_in[4];
    const float* Whh  = (const float*)d_in[5];
    const float* bih  = (const float*)d_in[6];
    const float* bhh  = (const float*)d_in[7];
    const float* Wlin = (const float*)d_in[8];
    const float* blin = (const float*)d_in[9];
    float* out = (float*)d_out;

    hipLaunchKernelGGL(init_kernel, dim3(1), dim3(256), 0, stream);
    hipLaunchKernelGGL(lstm_kernel, dim3(NBLK), dim3(THR), 0, stream,
                       x, h0, c0, Wih0, Wih, Whh, bih, bhh, Wlin, blin, out);
}

// Round 7
// 2736.801 us; speedup vs baseline: 5.2390x; 1.0331x over previous
//
#include <hip/hip_runtime.h>
#include <hip/hip_fp16.h>
#include <math.h>

#define Tn 1024
#define Bn 256
#define Hn 120
#define Ln 4
#define NBC 8                 // batch chunks of 32
#define NBCOL 32              // cols per chunk
#define NBLK (Ln*NBC)         // 32 blocks, one per (layer, bc)
#define THR 512               // 8 waves
#define Dd 8                  // ring depth
#define PADI 32
#define KPh 392               // col stride (elems); 392/2 dwords %32==4 -> same 2-way bank profile as 264

typedef _Float16 f16x8 __attribute__((ext_vector_type(8)));
typedef float    f32x4 __attribute__((ext_vector_type(4)));
typedef unsigned int u32x4 __attribute__((ext_vector_type(4)));
typedef unsigned short ushort_t;

template<int N> struct IC { static constexpr int value = N; };

// R20: latency-decoupled step. (1) ring load L(t+1) issued at step ENTRY
// (flies under GEMM+cell); (2) single per-step vmcnt(0) retires only
// ops issued a full phase earlier (~free); (3) prod/cons posts moved
// after barrier C (collective-safe: every wave's own vmcnt(0) preceded
// it) with prod delayed one step (epilogue posts Tn-1); (4) raw counted
// barriers (lgkmcnt-only) so vmem stays in flight across them; (5) h
// ping-pong in LDS (h(t) at 256*(t&1), bh fixed at 120..239) deletes
// the GEMM->cell barrier: MFMA and VALU overlap across waves (m114).
// A-fragments pair by LOGICAL k, so ping-pong needs no weight copies.
__device__ ushort_t g_ring[(size_t)3 * Dd * NBC * NBCOL * Hn]; // [l][slot][bc][b][cell]
__device__ int g_prod[3 * NBC * PADI];
__device__ int g_cons[Ln * NBC * PADI];
__device__ int g_abort;

__global__ __launch_bounds__(256) void init_kernel() {
    int idx = threadIdx.x;
    if (idx < 3 * NBC)  g_prod[idx * PADI] = -1;
    if (idx < Ln * NBC) g_cons[idx * PADI] = -1;
    if (idx == 0)       g_abort = 0;
}

#if __has_builtin(__builtin_amdgcn_exp2f)
__device__ __forceinline__ float hw_exp2(float x) { return __builtin_amdgcn_exp2f(x); }
#else
__device__ __forceinline__ float hw_exp2(float x) { return exp2f(x); }
#endif
#if __has_builtin(__builtin_amdgcn_rcpf)
__device__ __forceinline__ float hw_rcp(float x) { return __builtin_amdgcn_rcpf(x); }
#else
__device__ __forceinline__ float hw_rcp(float x) { return 1.0f / x; }
#endif
#define LOG2E_F 1.44269504f

__device__ __forceinline__ float sigm(float v) {
    return hw_rcp(1.0f + hw_exp2(-LOG2E_F * v));
}
__device__ __forceinline__ float tanh_fast(float v) {
    return 1.0f - 2.0f * hw_rcp(1.0f + hw_exp2(2.0f * LOG2E_F * v));
}

// raw barrier: waits LDS ops only; vmem stays in flight across it.
#define BAR_LGKM() asm volatile("s_waitcnt lgkmcnt(0)\ns_barrier" ::: "memory")

__device__ __forceinline__ void spin_wait(int* p, int tgt, int& dead, int& pc) {
    if (dead || pc >= tgt) return;
    int guard = 0, v;
    while ((v = __hip_atomic_load(p, __ATOMIC_RELAXED,
                                  __HIP_MEMORY_SCOPE_SYSTEM)) < tgt) {
        __builtin_amdgcn_s_sleep(1);
        if ((++guard & 127) == 0) {
            if (__hip_atomic_load(&g_abort, __ATOMIC_RELAXED,
                                  __HIP_MEMORY_SCOPE_SYSTEM)) { dead = 1; return; }
            if (guard > 60000) { atomicExch(&g_abort, 1); dead = 1; return; }
        }
    }
    pc = v;
}

// hx layout (LDS, f16): hxT[col 0..31][elem 0..391].
//   elems 120..239 : below-h(t) (l>0) or x(t)@120 (l=0), FIXED
//   elems 240..255 : zero pad (FIXED)
//   elems   0..119 : h(t) for even t   (ping)
//   elems 256..375 : h(t) for odd  t   (pong; h0 lives here)
// GEMM pairs A-frag (logical k) with LDS addr e + (e<120 ? hbR : 0).
__global__ __launch_bounds__(THR, 2) void lstm_kernel(
    const float* __restrict__ x,    const float* __restrict__ h0,
    const float* __restrict__ c0,   const float* __restrict__ Wih0,
    const float* __restrict__ Wih,  const float* __restrict__ Whh,
    const float* __restrict__ bih,  const float* __restrict__ bhh,
    const float* __restrict__ Wlin, const float* __restrict__ blin,
    float* __restrict__ out)
{
    __shared__ _Float16 hxT[NBCOL * KPh];   // 24.5 KB

    const int bx   = blockIdx.x;
    const int l    = bx >> 3;
    const int bc   = bx & 7;
    const int tid  = threadIdx.x;
    const int w    = tid >> 6;
    const int lane = tid & 63;
    const int quad = lane >> 4;
    const int l16  = lane & 15;
    const int bg0  = bc * NBCOL;
    const int mtn  = (w < 6) ? 4 : 3;           // m-tiles this wave
    const int mt0  = (w < 6) ? 4 * w : 24 + 3 * (w - 6);
    int dead = 0, pcb = -0x40000000, pca = -0x40000000;

    const float* WhhL = Whh + (size_t)l * 4 * Hn * Hn;
    const float* WihL = (l > 0) ? Wih + (size_t)(l - 1) * 4 * Hn * Hn : Whh;
    ushort_t* ringP = g_ring + (size_t)l * Dd * NBC * NBCOL * Hn;       // l<3
    const ushort_t* ringC =
        g_ring + (size_t)(l > 0 ? l - 1 : 0) * Dd * NBC * NBCOL * Hn;
    int* prodUp = &g_prod[(l > 0 ? ((l - 1) * NBC + bc) : 0) * PADI];
    int* prodMe = &g_prod[(l < 3 ? (l * NBC + bc) : 0) * PADI];
    int* consDn = &g_cons[(l < 3 ? ((l + 1) * NBC + bc) : 0) * PADI];
    int* consMe = &g_cons[(l * NBC + bc) * PADI];

    // ---- persistent A-fragments (weights, f16) in VGPRs.
    f16x8 a[4][8];
    #pragma unroll
    for (int m = 0; m < 4; ++m) {
        int rp = (mt0 + m) * 16 + l16;          // permuted row 0..479
        int cell = rp >> 2, gate = rp & 3;
        int orow = gate * Hn + cell;
        #pragma unroll
        for (int kt = 0; kt < 8; ++kt) {
            f16x8 av;
            #pragma unroll
            for (int j = 0; j < 8; ++j) {
                int k = kt * 32 + quad * 8 + j;
                float v = 0.f;
                if (m < mtn) {
                    if (k < Hn)            v = WhhL[orow * Hn + k];
                    else if (l == 0)       v = (k == Hn) ? Wih0[orow] : 0.f;
                    else if (k < 2 * Hn)   v = WihL[orow * Hn + (k - Hn)];
                }
                av[j] = (_Float16)v;
            }
            a[m][kt] = av;
        }
    }

    float bias_g[4][4];
    float cst[4][2];
    #pragma unroll
    for (int m = 0; m < 4; ++m) {
        int cell = (mt0 + m) * 4 + quad;
        #pragma unroll
        for (int g = 0; g < 4; ++g)
            bias_g[m][g] = (m < mtn)
                ? bih[l * 4 * Hn + g * Hn + cell] + bhh[l * 4 * Hn + g * Hn + cell]
                : 0.f;
        #pragma unroll
        for (int n = 0; n < 2; ++n) {
            int col = n * 16 + l16;
            cst[m][n] = (m < mtn) ? c0[(l * Bn + bg0 + col) * Hn + cell] : 0.f;
        }
    }

    const int cp_c = tid / 15, cp_g = tid % 15;   // 480 dwordx4 copy lanes
    const int oc_col = tid >> 3, oc_j = tid & 7;  // l3 out (tid<256)
    float wl[15];
    if (l == 3) {
        #pragma unroll
        for (int c2 = 0; c2 < 15; ++c2) wl[c2] = Wlin[oc_j * 15 + c2];
    }

    // hxT init: h0 -> pong region (256+); zero fixed mid region [120,256)
    for (int q = tid; q < NBCOL * Hn; q += THR) {
        int col = q / Hn, cell = q % Hn;
        hxT[col * KPh + 256 + cell] = (_Float16)h0[(l * Bn + bg0 + col) * Hn + cell];
    }
    for (int q = tid; q < NBCOL * 136; q += THR) {
        int col = q / 136, kk = 120 + q % 136;
        hxT[col * KPh + kk] = (_Float16)0.f;
    }
    __syncthreads();

    // ---- prologue: stage bh(0) (l>0) or x(0) (l=0)
    if (l > 0) {
        if (tid == 0) spin_wait(prodUp, 0, dead, pcb);
        __syncthreads();
        u32x4 v0 = {0,0,0,0};
        const ushort_t* base = ringC + ((size_t)(0 * NBC + bc)) * NBCOL * Hn;
        if (tid < 480) {
            const ushort_t* p = base + cp_c * Hn + cp_g * 8;
            asm volatile("global_load_dwordx4 %0, %1, off sc0 sc1"
                         : "=v"(v0) : "v"(p));
        }
        asm volatile("s_waitcnt vmcnt(0)" ::: "memory");
        if (tid < 480)
            *(u32x4*)&hxT[cp_c * KPh + 120 + cp_g * 8] = v0;
        __syncthreads();
        if (tid == 96) atomicExch(consMe, 0);   // bh(0) consumed from ring
    } else {
        if (tid < NBCOL) hxT[tid * KPh + 120] = (_Float16)x[bg0 + tid];
        __syncthreads();
    }

    auto run = [&](auto ktlc) {
        constexpr int KTL = decltype(ktlc)::value;
        for (int t = 0; t < Tn; ++t) {
            const int slotW = t & (Dd - 1);
            const int slotR = (t + 1) & (Dd - 1);
            const int hbR = ((t & 1) ^ 1) << 8;   // h(t-1) region
            const int hbW = (t & 1) << 8;         // h(t) region

            // ---- entry: per-wave cached spins, then issue next-step vmem
            if (l > 0 && (t + 1) < Tn) spin_wait(prodUp, t + 1, dead, pcb);
            if (l < 3 && t >= Dd)      spin_wait(consDn, t - Dd, dead, pca);

            u32x4 ld = {0, 0, 0, 0};
            float xr = 0.f;
            if (l > 0 && (t + 1) < Tn && tid < 480) {
                const ushort_t* p = ringC + (size_t)(slotR * NBC + bc) * NBCOL * Hn
                                  + cp_c * Hn + cp_g * 8;
                asm volatile("global_load_dwordx4 %0, %1, off sc0 sc1"
                             : "=v"(ld) : "v"(p));
            }
            if (l == 0 && (t + 1) < Tn && tid < NBCOL)
                xr = x[(t + 1) * Bn + bg0 + tid];

            // ---- GEMM over full K (h @ hbR, bh fixed)
            f32x4 acc[4][2];
            #pragma unroll
            for (int m = 0; m < 4; ++m)
                #pragma unroll
                for (int n = 0; n < 2; ++n) {
                    f32x4 z; z[0] = bias_g[m][0]; z[1] = bias_g[m][1];
                    z[2] = bias_g[m][2]; z[3] = bias_g[m][3];
                    acc[m][n] = z;
                }
            #pragma unroll
            for (int kt = 0; kt < KTL; ++kt) {
                const int e0 = kt * 32 + quad * 8;
                const int ao = e0 + ((e0 < 120) ? hbR : 0);
                f16x8 bfr[2];
                #pragma unroll
                for (int n = 0; n < 2; ++n)
                    bfr[n] = *(const f16x8*)&hxT[(n * 16 + l16) * KPh + ao];
                #pragma unroll
                for (int m = 0; m < 4; ++m)
                    if (m < mtn)
                        #pragma unroll
                        for (int n = 0; n < 2; ++n)
                            acc[m][n] = __builtin_amdgcn_mfma_f32_16x16x32_f16(
                                a[m][kt], bfr[n], acc[m][n], 0, 0, 0);
            }

            // ---- cell update straight after GEMM (no barrier: writes hbW,
            // other waves still read hbR/bh -- disjoint LDS regions)
            #pragma unroll
            for (int m = 0; m < 4; ++m) {
                if (m >= mtn) continue;
                #pragma unroll
                for (int n = 0; n < 2; ++n) {
                    int col = n * 16 + l16;
                    int cell = (mt0 + m) * 4 + quad;
                    float ig = sigm(acc[m][n][0]);
                    float fg = sigm(acc[m][n][1]);
                    float gg = tanh_fast(acc[m][n][2]);
                    float og = sigm(acc[m][n][3]);
                    float cn = fmaf(fg, cst[m][n], ig * gg);
                    cst[m][n] = cn;
                    float hn = og * tanh_fast(cn);
                    hxT[col * KPh + hbW + cell] = (_Float16)hn;
                }
            }
            BAR_LGKM();   // B: h(t) visible to all waves

            // ---- single per-step drain: retires S(t-1) (1 step old) and
            // L(t+1)/x(t+1) (issued at entry, flew under GEMM+cell)
            asm volatile("s_waitcnt vmcnt(0)" ::: "memory");
            __builtin_amdgcn_sched_barrier(0);

            // stage bh(t+1)/x(t+1) into fixed region
            if (l > 0 && (t + 1) < Tn && tid < 480)
                *(u32x4*)&hxT[cp_c * KPh + 120 + cp_g * 8] = ld;
            if (l == 0 && (t + 1) < Tn && tid < NBCOL)
                hxT[tid * KPh + 120] = (_Float16)xr;

            // issue ring stores S(t) (h(t) @ hbW); drained next step
            if (l < 3 && tid < 480) {
                u32x4 v0 = *(const u32x4*)&hxT[cp_c * KPh + hbW + cp_g * 8];
                ushort_t* p0 = ringP + (size_t)(slotW * NBC + bc) * NBCOL * Hn
                             + cp_c * Hn + cp_g * 8;
                asm volatile("global_store_dwordx4 %0, %1, off sc0 sc1"
                             :: "v"(p0), "v"(v0) : "memory");
            }
            if (l == 3 && tid < NBCOL * 8) {
                float pout = 0.f;
                const _Float16* hrow = &hxT[oc_col * KPh + hbW + oc_j * 15];
                #pragma unroll
                for (int c2 = 0; c2 < 15; ++c2)
                    pout = fmaf(wl[c2], (float)hrow[c2], pout);
                pout += __shfl_down(pout, 4, 8);
                pout += __shfl_down(pout, 2, 8);
                pout += __shfl_down(pout, 1, 8);
                if (oc_j == 0) out[t * Bn + bg0 + oc_col] = pout + blin[0];
            }
            BAR_LGKM();   // C: staging writes + S's LDS reads complete

            // ---- posts (collective-safe: every wave's vmcnt(0) was pre-C)
            if (l < 3 && tid == 0 && t > 0) atomicExch(prodMe, t - 1);
            if (l > 0 && tid == 96)         atomicExch(consMe, t + 1);
        }
    };
    if (l == 0) run(IC<4>{});
    else        run(IC<8>{});

    // ---- epilogue: retire final ring stores, post last prod
    if (l < 3) {
        asm volatile("s_waitcnt vmcnt(0)" ::: "memory");
        __syncthreads();
        if (tid == 0) atomicExch(prodMe, Tn - 1);
    }
}

extern "C" void kernel_launch(void* const* d_in, const int* in_sizes, int n_in,
                              void* d_out, int out_size, void* d_ws, size_t ws_size,
                              hipStream_t stream) {
    const float* x    = (const float*)d_in[0];
    const float* h0   = (const float*)d_in[1];
    const float* c0   = (const float*)d_in[2];
    const float* Wih0 = (const float*)d_in[3];
    const float* Wih  = (const float*)d_in[4];
    const float* Whh  = (const float*)d_in[5];
    const float* bih  = (const float*)d_in[6];
    const float* bhh  = (const float*)d_in[7];
    const float* Wlin = (const float*)d_in[8];
    const float* blin = (const float*)d_in[9];
    float* out = (float*)d_out;

    hipLaunchKernelGGL(init_kernel, dim3(1), dim3(256), 0, stream);
    hipLaunchKernelGGL(lstm_kernel, dim3(NBLK), dim3(THR), 0, stream,
                       x, h0, c0, Wih0, Wih, Whh, bih, bhh, Wlin, blin, out);
}

// Round 8
// 2695.334 us; speedup vs baseline: 5.3196x; 1.0154x over previous
//
#include <hip/hip_runtime.h>
#include <hip/hip_fp16.h>
#include <math.h>

#define Tn 1024
#define Bn 256
#define Hn 120
#define Ln 4
#define NBC 8                 // batch chunks of 32
#define NBCOL 32              // cols per chunk
#define NBLK (Ln*NBC)         // 32 blocks, one per (layer, bc)
#define THR 512               // 8 waves
#define Dd 16                 // ring depth (was 8): slack for batched flags
#define PADI 32
#define KPh 392               // col stride (elems)

typedef _Float16 f16x8 __attribute__((ext_vector_type(8)));
typedef float    f32x4 __attribute__((ext_vector_type(4)));
typedef unsigned int u32x4 __attribute__((ext_vector_type(4)));
typedef unsigned short ushort_t;

template<int N> struct IC { static constexpr int value = N; };

// R21: duration is CLOCK-INVARIANT (disp0 vs steady: same dur, 2.6x util
// ratio) => period set by wall-clock flag latencies, not cycles. So:
// (1) 4-step BATCHED handshake, ring depth 16: spins only at t%4==0
//     (prod target min(t+4,Tn-1); cons guard t-13), posts only at t%4==3
//     (prod=t-1, cons=t+1; both drained by that step's vmcnt(0)).
//     Offset band [7,13] < 16 -> polls nearly always pc-cache-satisfied.
// (2) posts are fire-and-forget relaxed system stores (no exch wait).
// (3) GEMM/cell split m{0,1}/m{2,3}: cell(01)'s trans burst overlaps
//     gemm(23)'s MFMAs in the in-order issue stream.
__device__ ushort_t g_ring[(size_t)3 * Dd * NBC * NBCOL * Hn]; // [l][slot][bc][b][cell]
__device__ int g_prod[3 * NBC * PADI];
__device__ int g_cons[Ln * NBC * PADI];
__device__ int g_abort;

__global__ __launch_bounds__(256) void init_kernel() {
    int idx = threadIdx.x;
    if (idx < 3 * NBC)  g_prod[idx * PADI] = -1;
    if (idx < Ln * NBC) g_cons[idx * PADI] = -1;
    if (idx == 0)       g_abort = 0;
}

#if __has_builtin(__builtin_amdgcn_exp2f)
__device__ __forceinline__ float hw_exp2(float x) { return __builtin_amdgcn_exp2f(x); }
#else
__device__ __forceinline__ float hw_exp2(float x) { return exp2f(x); }
#endif
#if __has_builtin(__builtin_amdgcn_rcpf)
__device__ __forceinline__ float hw_rcp(float x) { return __builtin_amdgcn_rcpf(x); }
#else
__device__ __forceinline__ float hw_rcp(float x) { return 1.0f / x; }
#endif
#define LOG2E_F 1.44269504f

__device__ __forceinline__ float sigm(float v) {
    return hw_rcp(1.0f + hw_exp2(-LOG2E_F * v));
}
__device__ __forceinline__ float tanh_fast(float v) {
    return 1.0f - 2.0f * hw_rcp(1.0f + hw_exp2(2.0f * LOG2E_F * v));
}

// raw barrier: waits LDS ops only; vmem stays in flight across it.
#define BAR_LGKM() asm volatile("s_waitcnt lgkmcnt(0)\ns_barrier" ::: "memory")

__device__ __forceinline__ void spin_wait(int* p, int tgt, int& dead, int& pc) {
    if (dead || pc >= tgt) return;
    int guard = 0, v;
    while ((v = __hip_atomic_load(p, __ATOMIC_RELAXED,
                                  __HIP_MEMORY_SCOPE_SYSTEM)) < tgt) {
        __builtin_amdgcn_s_sleep(1);
        if ((++guard & 127) == 0) {
            if (__hip_atomic_load(&g_abort, __ATOMIC_RELAXED,
                                  __HIP_MEMORY_SCOPE_SYSTEM)) { dead = 1; return; }
            if (guard > 60000) { atomicExch(&g_abort, 1); dead = 1; return; }
        }
    }
    pc = v;
}

__device__ __forceinline__ void post_flag(int* p, int v) {
    __hip_atomic_store(p, v, __ATOMIC_RELAXED, __HIP_MEMORY_SCOPE_SYSTEM);
}

// hx layout (LDS, f16): hxT[col 0..31][elem 0..391].
//   elems 120..239 : below-h(t) (l>0) or x(t)@120 (l=0), FIXED
//   elems 240..255 : zero pad (FIXED)
//   elems   0..119 : h(t) for even t   (ping)
//   elems 256..375 : h(t) for odd  t   (pong; h0 lives here)
__global__ __launch_bounds__(THR, 2) void lstm_kernel(
    const float* __restrict__ x,    const float* __restrict__ h0,
    const float* __restrict__ c0,   const float* __restrict__ Wih0,
    const float* __restrict__ Wih,  const float* __restrict__ Whh,
    const float* __restrict__ bih,  const float* __restrict__ bhh,
    const float* __restrict__ Wlin, const float* __restrict__ blin,
    float* __restrict__ out)
{
    __shared__ _Float16 hxT[NBCOL * KPh];   // 24.5 KB

    const int bx   = blockIdx.x;
    const int l    = bx >> 3;
    const int bc   = bx & 7;
    const int tid  = threadIdx.x;
    const int w    = tid >> 6;
    const int lane = tid & 63;
    const int quad = lane >> 4;
    const int l16  = lane & 15;
    const int bg0  = bc * NBCOL;
    const int mtn  = (w < 6) ? 4 : 3;           // m-tiles this wave
    const int mt0  = (w < 6) ? 4 * w : 24 + 3 * (w - 6);
    int dead = 0, pcb = -0x40000000, pca = -0x40000000;

    const float* WhhL = Whh + (size_t)l * 4 * Hn * Hn;
    const float* WihL = (l > 0) ? Wih + (size_t)(l - 1) * 4 * Hn * Hn : Whh;
    ushort_t* ringP = g_ring + (size_t)l * Dd * NBC * NBCOL * Hn;       // l<3
    const ushort_t* ringC =
        g_ring + (size_t)(l > 0 ? l - 1 : 0) * Dd * NBC * NBCOL * Hn;
    int* prodUp = &g_prod[(l > 0 ? ((l - 1) * NBC + bc) : 0) * PADI];
    int* prodMe = &g_prod[(l < 3 ? (l * NBC + bc) : 0) * PADI];
    int* consDn = &g_cons[(l < 3 ? ((l + 1) * NBC + bc) : 0) * PADI];
    int* consMe = &g_cons[(l * NBC + bc) * PADI];

    // ---- persistent A-fragments (weights, f16) in VGPRs.
    f16x8 a[4][8];
    #pragma unroll
    for (int m = 0; m < 4; ++m) {
        int rp = (mt0 + m) * 16 + l16;          // permuted row 0..479
        int cell = rp >> 2, gate = rp & 3;
        int orow = gate * Hn + cell;
        #pragma unroll
        for (int kt = 0; kt < 8; ++kt) {
            f16x8 av;
            #pragma unroll
            for (int j = 0; j < 8; ++j) {
                int k = kt * 32 + quad * 8 + j;
                float v = 0.f;
                if (m < mtn) {
                    if (k < Hn)            v = WhhL[orow * Hn + k];
                    else if (l == 0)       v = (k == Hn) ? Wih0[orow] : 0.f;
                    else if (k < 2 * Hn)   v = WihL[orow * Hn + (k - Hn)];
                }
                av[j] = (_Float16)v;
            }
            a[m][kt] = av;
        }
    }

    float bias_g[4][4];
    float cst[4][2];
    #pragma unroll
    for (int m = 0; m < 4; ++m) {
        int cell = (mt0 + m) * 4 + quad;
        #pragma unroll
        for (int g = 0; g < 4; ++g)
            bias_g[m][g] = (m < mtn)
                ? bih[l * 4 * Hn + g * Hn + cell] + bhh[l * 4 * Hn + g * Hn + cell]
                : 0.f;
        #pragma unroll
        for (int n = 0; n < 2; ++n) {
            int col = n * 16 + l16;
            cst[m][n] = (m < mtn) ? c0[(l * Bn + bg0 + col) * Hn + cell] : 0.f;
        }
    }

    const int cp_c = tid / 15, cp_g = tid % 15;   // 480 dwordx4 copy lanes
    const int oc_col = tid >> 3, oc_j = tid & 7;  // l3 out (tid<256)
    float wl[15];
    if (l == 3) {
        #pragma unroll
        for (int c2 = 0; c2 < 15; ++c2) wl[c2] = Wlin[oc_j * 15 + c2];
    }

    // hxT init: h0 -> pong region (256+); zero fixed mid region [120,256)
    for (int q = tid; q < NBCOL * Hn; q += THR) {
        int col = q / Hn, cell = q % Hn;
        hxT[col * KPh + 256 + cell] = (_Float16)h0[(l * Bn + bg0 + col) * Hn + cell];
    }
    for (int q = tid; q < NBCOL * 136; q += THR) {
        int col = q / 136, kk = 120 + q % 136;
        hxT[col * KPh + kk] = (_Float16)0.f;
    }
    __syncthreads();

    // ---- prologue: stage bh(0) (l>0) or x(0) (l=0)
    if (l > 0) {
        spin_wait(prodUp, 0, dead, pcb);        // per-wave; prod=2 covers slot0
        u32x4 v0 = {0,0,0,0};
        const ushort_t* base = ringC + ((size_t)(0 * NBC + bc)) * NBCOL * Hn;
        if (tid < 480) {
            const ushort_t* p = base + cp_c * Hn + cp_g * 8;
            asm volatile("global_load_dwordx4 %0, %1, off sc0 sc1"
                         : "=v"(v0) : "v"(p));
        }
        asm volatile("s_waitcnt vmcnt(0)" ::: "memory");
        if (tid < 480)
            *(u32x4*)&hxT[cp_c * KPh + 120 + cp_g * 8] = v0;
        __syncthreads();
        if (tid == 96) post_flag(consMe, 0);
    } else {
        if (tid < NBCOL) hxT[tid * KPh + 120] = (_Float16)x[bg0 + tid];
        __syncthreads();
    }

    auto run = [&](auto ktlc) {
        constexpr int KTL = decltype(ktlc)::value;
        for (int t = 0; t < Tn; ++t) {
            const int slotW = t & (Dd - 1);
            const int slotR = (t + 1) & (Dd - 1);
            const int hbR = ((t & 1) ^ 1) << 8;   // h(t-1) region
            const int hbW = (t & 1) << 8;         // h(t) region

            // ---- batched spins (every 4 steps; pc-cache skips the rest)
            if ((t & 3) == 0) {
                if (l > 0) {
                    int tgt = (t + 4 < Tn) ? t + 4 : Tn - 1;
                    spin_wait(prodUp, tgt, dead, pcb);
                }
                if (l < 3 && t >= 16)
                    spin_wait(consDn, t - 13, dead, pca);
            }

            // ---- issue next-step vmem at entry (flies under GEMM+cell)
            u32x4 ld = {0, 0, 0, 0};
            float xr = 0.f;
            if (l > 0 && (t + 1) < Tn && tid < 480) {
                const ushort_t* p = ringC + (size_t)(slotR * NBC + bc) * NBCOL * Hn
                                  + cp_c * Hn + cp_g * 8;
                asm volatile("global_load_dwordx4 %0, %1, off sc0 sc1"
                             : "=v"(ld) : "v"(p));
            }
            if (l == 0 && (t + 1) < Tn && tid < NBCOL)
                xr = x[(t + 1) * Bn + bg0 + tid];

            // ---- GEMM + cell, split in halves so cell(01)'s trans burst
            // overlaps gemm(23)'s MFMAs (independent; in-order issue mixes)
            f32x4 acc[4][2];
            #pragma unroll
            for (int m = 0; m < 4; ++m)
                #pragma unroll
                for (int n = 0; n < 2; ++n) {
                    f32x4 z; z[0] = bias_g[m][0]; z[1] = bias_g[m][1];
                    z[2] = bias_g[m][2]; z[3] = bias_g[m][3];
                    acc[m][n] = z;
                }

            #pragma unroll
            for (int half = 0; half < 2; ++half) {
                const int M0 = half * 2;
                #pragma unroll
                for (int kt = 0; kt < KTL; ++kt) {
                    const int e0 = kt * 32 + quad * 8;
                    const int ao = e0 + ((e0 < 120) ? hbR : 0);
                    f16x8 bfr[2];
                    #pragma unroll
                    for (int n = 0; n < 2; ++n)
                        bfr[n] = *(const f16x8*)&hxT[(n * 16 + l16) * KPh + ao];
                    #pragma unroll
                    for (int m = M0; m < M0 + 2; ++m)
                        if (m < mtn)
                            #pragma unroll
                            for (int n = 0; n < 2; ++n)
                                acc[m][n] = __builtin_amdgcn_mfma_f32_16x16x32_f16(
                                    a[m][kt], bfr[n], acc[m][n], 0, 0, 0);
                }
                #pragma unroll
                for (int m = M0; m < M0 + 2; ++m) {
                    if (m >= mtn) continue;
                    #pragma unroll
                    for (int n = 0; n < 2; ++n) {
                        int col = n * 16 + l16;
                        int cell = (mt0 + m) * 4 + quad;
                        float ig = sigm(acc[m][n][0]);
                        float fg = sigm(acc[m][n][1]);
                        float gg = tanh_fast(acc[m][n][2]);
                        float og = sigm(acc[m][n][3]);
                        float cn = fmaf(fg, cst[m][n], ig * gg);
                        cst[m][n] = cn;
                        float hn = og * tanh_fast(cn);
                        hxT[col * KPh + hbW + cell] = (_Float16)hn;
                    }
                }
            }
            BAR_LGKM();   // B: h(t) visible to all waves

            // ---- single per-step drain: retires S(t-1) (1 step old) and
            // L(t+1)/x(t+1) (issued at entry, flew under GEMM+cell)
            asm volatile("s_waitcnt vmcnt(0)" ::: "memory");
            __builtin_amdgcn_sched_barrier(0);

            // stage bh(t+1)/x(t+1) into fixed region
            if (l > 0 && (t + 1) < Tn && tid < 480)
                *(u32x4*)&hxT[cp_c * KPh + 120 + cp_g * 8] = ld;
            if (l == 0 && (t + 1) < Tn && tid < NBCOL)
                hxT[tid * KPh + 120] = (_Float16)xr;

            // issue ring stores S(t) (h(t) @ hbW); drained next step
            if (l < 3 && tid < 480) {
                u32x4 v0 = *(const u32x4*)&hxT[cp_c * KPh + hbW + cp_g * 8];
                ushort_t* p0 = ringP + (size_t)(slotW * NBC + bc) * NBCOL * Hn
                             + cp_c * Hn + cp_g * 8;
                asm volatile("global_store_dwordx4 %0, %1, off sc0 sc1"
                             :: "v"(p0), "v"(v0) : "memory");
            }
            if (l == 3 && tid < NBCOL * 8) {
                float pout = 0.f;
                const _Float16* hrow = &hxT[oc_col * KPh + hbW + oc_j * 15];
                #pragma unroll
                for (int c2 = 0; c2 < 15; ++c2)
                    pout = fmaf(wl[c2], (float)hrow[c2], pout);
                pout += __shfl_down(pout, 4, 8);
                pout += __shfl_down(pout, 2, 8);
                pout += __shfl_down(pout, 1, 8);
                if (oc_j == 0) out[t * Bn + bg0 + oc_col] = pout + blin[0];
            }
            BAR_LGKM();   // C: staging writes + S's LDS reads complete

            // ---- batched posts (values drained by this step's vmcnt(0))
            if ((t & 3) == 3) {
                if (l < 3 && tid == 0)  post_flag(prodMe, t - 1);
                if (l > 0 && tid == 96) post_flag(consMe, t + 1);
            }
        }
    };
    if (l == 0) run(IC<4>{});
    else        run(IC<8>{});

    // ---- epilogue: retire final ring stores, post last prod
    if (l < 3) {
        asm volatile("s_waitcnt vmcnt(0)" ::: "memory");
        __syncthreads();
        if (tid == 0) post_flag(prodMe, Tn - 1);
    }
}

extern "C" void kernel_launch(void* const* d_in, const int* in_sizes, int n_in,
                              void* d_out, int out_size, void* d_ws, size_t ws_size,
                              hipStream_t stream) {
    const float* x    = (const float*)d_in[0];
    const float* h0   = (const float*)d_in[1];
    const float* c0   = (const float*)d_in[2];
    const float* Wih0 = (const float*)d_in[3];
    const float* Wih  = (const float*)d_in[4];
    const float* Whh  = (const float*)d_in[5];
    const float* bih  = (const float*)d_in[6];
    const float* bhh  = (const float*)d_in[7];
    const float* Wlin = (const float*)d_in[8];
    const float* blin = (const float*)d_in[9];
    float* out = (float*)d_out;

    hipLaunchKernelGGL(init_kernel, dim3(1), dim3(256), 0, stream);
    hipLaunchKernelGGL(lstm_kernel, dim3(NBLK), dim3(THR), 0, stream,
                       x, h0, c0, Wih0, Wih, Whh, bih, bhh, Wlin, blin, out);
}

// Round 9
// 1697.423 us; speedup vs baseline: 8.4469x; 1.5879x over previous
//
#include <hip/hip_runtime.h>
#include <hip/hip_fp16.h>
#include <math.h>

#define Tn 1024
#define Bn 256
#define Hn 120
#define Ln 4
#define NBC 16                // batch chunks of 16
#define NBCOL 16              // cols per chunk
#define NBLK (Ln*NBC)         // 64 blocks, one per (layer, bc)
#define THR 512               // 8 waves
#define Dd 16                 // ring depth
#define PADI 32
#define KPh 392               // col stride (elems)

typedef _Float16 f16x8 __attribute__((ext_vector_type(8)));
typedef float    f32x4 __attribute__((ext_vector_type(4)));
typedef unsigned int u32x4 __attribute__((ext_vector_type(4)));
typedef unsigned short ushort_t;

template<int N> struct IC { static constexpr int value = N; };

// R22: R21 with NBC 16 (16-col chunks, 64 blocks / 64 CUs). R20/R21 nulls
// proved vmem round-trips and flag latency are NOT the limiter; cycle
// accounting says the body is compute-bound at the DVFS clock, dominated
// by the per-SIMD transcendental burst (1280 cyc) + MFMA issue (620).
// Halving per-block work halves both; the n-dim collapses to ONE fully-
// occupied 16-col MFMA tile. Protocol identical to R21 (4-step batched
// flags, depth-16 ring, entry-issued loads, single per-step vmcnt(0),
// lgkm-only barriers, h ping-pong, GEMM/cell half-split).
__device__ ushort_t g_ring[(size_t)3 * Dd * NBC * NBCOL * Hn]; // [l][slot][bc][b][cell]
__device__ int g_prod[3 * NBC * PADI];
__device__ int g_cons[Ln * NBC * PADI];
__device__ int g_abort;

__global__ __launch_bounds__(256) void init_kernel() {
    int idx = threadIdx.x;
    if (idx < 3 * NBC)  g_prod[idx * PADI] = -1;
    if (idx < Ln * NBC) g_cons[idx * PADI] = -1;
    if (idx == 0)       g_abort = 0;
}

#if __has_builtin(__builtin_amdgcn_exp2f)
__device__ __forceinline__ float hw_exp2(float x) { return __builtin_amdgcn_exp2f(x); }
#else
__device__ __forceinline__ float hw_exp2(float x) { return exp2f(x); }
#endif
#if __has_builtin(__builtin_amdgcn_rcpf)
__device__ __forceinline__ float hw_rcp(float x) { return __builtin_amdgcn_rcpf(x); }
#else
__device__ __forceinline__ float hw_rcp(float x) { return 1.0f / x; }
#endif
#define LOG2E_F 1.44269504f

__device__ __forceinline__ float sigm(float v) {
    return hw_rcp(1.0f + hw_exp2(-LOG2E_F * v));
}
__device__ __forceinline__ float tanh_fast(float v) {
    return 1.0f - 2.0f * hw_rcp(1.0f + hw_exp2(2.0f * LOG2E_F * v));
}

// raw barrier: waits LDS ops only; vmem stays in flight across it.
#define BAR_LGKM() asm volatile("s_waitcnt lgkmcnt(0)\ns_barrier" ::: "memory")

__device__ __forceinline__ void spin_wait(int* p, int tgt, int& dead, int& pc) {
    if (dead || pc >= tgt) return;
    int guard = 0, v;
    while ((v = __hip_atomic_load(p, __ATOMIC_RELAXED,
                                  __HIP_MEMORY_SCOPE_SYSTEM)) < tgt) {
        __builtin_amdgcn_s_sleep(1);
        if ((++guard & 127) == 0) {
            if (__hip_atomic_load(&g_abort, __ATOMIC_RELAXED,
                                  __HIP_MEMORY_SCOPE_SYSTEM)) { dead = 1; return; }
            if (guard > 60000) { atomicExch(&g_abort, 1); dead = 1; return; }
        }
    }
    pc = v;
}

__device__ __forceinline__ void post_flag(int* p, int v) {
    __hip_atomic_store(p, v, __ATOMIC_RELAXED, __HIP_MEMORY_SCOPE_SYSTEM);
}

// hx layout (LDS, f16): hxT[col 0..15][elem 0..391].
//   elems 120..239 : below-h(t) (l>0) or x(t)@120 (l=0), FIXED
//   elems 240..255 : zero pad (FIXED)
//   elems   0..119 : h(t) for even t   (ping)
//   elems 256..375 : h(t) for odd  t   (pong; h0 lives here)
__global__ __launch_bounds__(THR, 2) void lstm_kernel(
    const float* __restrict__ x,    const float* __restrict__ h0,
    const float* __restrict__ c0,   const float* __restrict__ Wih0,
    const float* __restrict__ Wih,  const float* __restrict__ Whh,
    const float* __restrict__ bih,  const float* __restrict__ bhh,
    const float* __restrict__ Wlin, const float* __restrict__ blin,
    float* __restrict__ out)
{
    __shared__ _Float16 hxT[NBCOL * KPh];   // 12.3 KB

    const int bx   = blockIdx.x;
    const int l    = bx >> 4;
    const int bc   = bx & 15;
    const int tid  = threadIdx.x;
    const int w    = tid >> 6;
    const int lane = tid & 63;
    const int quad = lane >> 4;
    const int l16  = lane & 15;
    const int bg0  = bc * NBCOL;
    const int mtn  = (w < 6) ? 4 : 3;           // m-tiles this wave
    const int mt0  = (w < 6) ? 4 * w : 24 + 3 * (w - 6);
    int dead = 0, pcb = -0x40000000, pca = -0x40000000;

    const float* WhhL = Whh + (size_t)l * 4 * Hn * Hn;
    const float* WihL = (l > 0) ? Wih + (size_t)(l - 1) * 4 * Hn * Hn : Whh;
    ushort_t* ringP = g_ring + (size_t)l * Dd * NBC * NBCOL * Hn;       // l<3
    const ushort_t* ringC =
        g_ring + (size_t)(l > 0 ? l - 1 : 0) * Dd * NBC * NBCOL * Hn;
    int* prodUp = &g_prod[(l > 0 ? ((l - 1) * NBC + bc) : 0) * PADI];
    int* prodMe = &g_prod[(l < 3 ? (l * NBC + bc) : 0) * PADI];
    int* consDn = &g_cons[(l < 3 ? ((l + 1) * NBC + bc) : 0) * PADI];
    int* consMe = &g_cons[(l * NBC + bc) * PADI];

    // ---- persistent A-fragments (weights, f16) in VGPRs.
    f16x8 a[4][8];
    #pragma unroll
    for (int m = 0; m < 4; ++m) {
        int rp = (mt0 + m) * 16 + l16;          // permuted row 0..479
        int cell = rp >> 2, gate = rp & 3;
        int orow = gate * Hn + cell;
        #pragma unroll
        for (int kt = 0; kt < 8; ++kt) {
            f16x8 av;
            #pragma unroll
            for (int j = 0; j < 8; ++j) {
                int k = kt * 32 + quad * 8 + j;
                float v = 0.f;
                if (m < mtn) {
                    if (k < Hn)            v = WhhL[orow * Hn + k];
                    else if (l == 0)       v = (k == Hn) ? Wih0[orow] : 0.f;
                    else if (k < 2 * Hn)   v = WihL[orow * Hn + (k - Hn)];
                }
                av[j] = (_Float16)v;
            }
            a[m][kt] = av;
        }
    }

    float bias_g[4][4];
    float cst[4];
    #pragma unroll
    for (int m = 0; m < 4; ++m) {
        int cell = (mt0 + m) * 4 + quad;
        #pragma unroll
        for (int g = 0; g < 4; ++g)
            bias_g[m][g] = (m < mtn)
                ? bih[l * 4 * Hn + g * Hn + cell] + bhh[l * 4 * Hn + g * Hn + cell]
                : 0.f;
        cst[m] = (m < mtn) ? c0[(l * Bn + bg0 + l16) * Hn + cell] : 0.f;
    }

    const int cp_c = tid / 15, cp_g = tid % 15;   // 240 dwordx4 copy lanes
    const int oc_col = tid >> 3, oc_j = tid & 7;  // l3 out (tid<128)
    float wl[15];
    if (l == 3) {
        #pragma unroll
        for (int c2 = 0; c2 < 15; ++c2) wl[c2] = Wlin[oc_j * 15 + c2];
    }

    // hxT init: h0 -> pong region (256+); zero fixed mid region [120,256)
    for (int q = tid; q < NBCOL * Hn; q += THR) {
        int col = q / Hn, cell = q % Hn;
        hxT[col * KPh + 256 + cell] = (_Float16)h0[(l * Bn + bg0 + col) * Hn + cell];
    }
    for (int q = tid; q < NBCOL * 136; q += THR) {
        int col = q / 136, kk = 120 + q % 136;
        hxT[col * KPh + kk] = (_Float16)0.f;
    }
    __syncthreads();

    // ---- prologue: stage bh(0) (l>0) or x(0) (l=0)
    if (l > 0) {
        spin_wait(prodUp, 0, dead, pcb);
        u32x4 v0 = {0,0,0,0};
        const ushort_t* base = ringC + ((size_t)(0 * NBC + bc)) * NBCOL * Hn;
        if (tid < 240) {
            const ushort_t* p = base + cp_c * Hn + cp_g * 8;
            asm volatile("global_load_dwordx4 %0, %1, off sc0 sc1"
                         : "=v"(v0) : "v"(p));
        }
        asm volatile("s_waitcnt vmcnt(0)" ::: "memory");
        if (tid < 240)
            *(u32x4*)&hxT[cp_c * KPh + 120 + cp_g * 8] = v0;
        __syncthreads();
        if (tid == 96) post_flag(consMe, 0);
    } else {
        if (tid < NBCOL) hxT[tid * KPh + 120] = (_Float16)x[bg0 + tid];
        __syncthreads();
    }

    auto run = [&](auto ktlc) {
        constexpr int KTL = decltype(ktlc)::value;
        for (int t = 0; t < Tn; ++t) {
            const int slotW = t & (Dd - 1);
            const int slotR = (t + 1) & (Dd - 1);
            const int hbR = ((t & 1) ^ 1) << 8;   // h(t-1) region
            const int hbW = (t & 1) << 8;         // h(t) region

            // ---- batched spins (every 4 steps; pc-cache skips the rest)
            if ((t & 3) == 0) {
                if (l > 0) {
                    int tgt = (t + 4 < Tn) ? t + 4 : Tn - 1;
                    spin_wait(prodUp, tgt, dead, pcb);
                }
                if (l < 3 && t >= 16)
                    spin_wait(consDn, t - 13, dead, pca);
            }

            // ---- issue next-step vmem at entry (flies under GEMM+cell)
            u32x4 ld = {0, 0, 0, 0};
            float xr = 0.f;
            if (l > 0 && (t + 1) < Tn && tid < 240) {
                const ushort_t* p = ringC + (size_t)(slotR * NBC + bc) * NBCOL * Hn
                                  + cp_c * Hn + cp_g * 8;
                asm volatile("global_load_dwordx4 %0, %1, off sc0 sc1"
                             : "=v"(ld) : "v"(p));
            }
            if (l == 0 && (t + 1) < Tn && tid < NBCOL)
                xr = x[(t + 1) * Bn + bg0 + tid];

            // ---- GEMM + cell, split in halves (cell(01) trans overlaps
            // gemm(23) MFMAs in the in-order issue stream)
            f32x4 acc[4];
            #pragma unroll
            for (int m = 0; m < 4; ++m) {
                f32x4 z; z[0] = bias_g[m][0]; z[1] = bias_g[m][1];
                z[2] = bias_g[m][2]; z[3] = bias_g[m][3];
                acc[m] = z;
            }

            #pragma unroll
            for (int half = 0; half < 2; ++half) {
                const int M0 = half * 2;
                #pragma unroll
                for (int kt = 0; kt < KTL; ++kt) {
                    const int e0 = kt * 32 + quad * 8;
                    const int ao = e0 + ((e0 < 120) ? hbR : 0);
                    f16x8 bfr = *(const f16x8*)&hxT[l16 * KPh + ao];
                    #pragma unroll
                    for (int m = M0; m < M0 + 2; ++m)
                        if (m < mtn)
                            acc[m] = __builtin_amdgcn_mfma_f32_16x16x32_f16(
                                a[m][kt], bfr, acc[m], 0, 0, 0);
                }
                #pragma unroll
                for (int m = M0; m < M0 + 2; ++m) {
                    if (m >= mtn) continue;
                    int cell = (mt0 + m) * 4 + quad;
                    float ig = sigm(acc[m][0]);
                    float fg = sigm(acc[m][1]);
                    float gg = tanh_fast(acc[m][2]);
                    float og = sigm(acc[m][3]);
                    float cn = fmaf(fg, cst[m], ig * gg);
                    cst[m] = cn;
                    float hn = og * tanh_fast(cn);
                    hxT[l16 * KPh + hbW + cell] = (_Float16)hn;
                }
            }
            BAR_LGKM();   // B: h(t) visible to all waves

            // ---- single per-step drain: retires S(t-1) (1 step old) and
            // L(t+1)/x(t+1) (issued at entry, flew under GEMM+cell)
            asm volatile("s_waitcnt vmcnt(0)" ::: "memory");
            __builtin_amdgcn_sched_barrier(0);

            // stage bh(t+1)/x(t+1) into fixed region
            if (l > 0 && (t + 1) < Tn && tid < 240)
                *(u32x4*)&hxT[cp_c * KPh + 120 + cp_g * 8] = ld;
            if (l == 0 && (t + 1) < Tn && tid < NBCOL)
                hxT[tid * KPh + 120] = (_Float16)xr;

            // issue ring stores S(t) (h(t) @ hbW); drained next step
            if (l < 3 && tid < 240) {
                u32x4 v0 = *(const u32x4*)&hxT[cp_c * KPh + hbW + cp_g * 8];
                ushort_t* p0 = ringP + (size_t)(slotW * NBC + bc) * NBCOL * Hn
                             + cp_c * Hn + cp_g * 8;
                asm volatile("global_store_dwordx4 %0, %1, off sc0 sc1"
                             :: "v"(p0), "v"(v0) : "memory");
            }
            if (l == 3 && tid < NBCOL * 8) {
                float pout = 0.f;
                const _Float16* hrow = &hxT[oc_col * KPh + hbW + oc_j * 15];
                #pragma unroll
                for (int c2 = 0; c2 < 15; ++c2)
                    pout = fmaf(wl[c2], (float)hrow[c2], pout);
                pout += __shfl_down(pout, 4, 8);
                pout += __shfl_down(pout, 2, 8);
                pout += __shfl_down(pout, 1, 8);
                if (oc_j == 0) out[t * Bn + bg0 + oc_col] = pout + blin[0];
            }
            BAR_LGKM();   // C: staging writes + S's LDS reads complete

            // ---- batched posts (values drained by this step's vmcnt(0))
            if ((t & 3) == 3) {
                if (l < 3 && tid == 0)  post_flag(prodMe, t - 1);
                if (l > 0 && tid == 96) post_flag(consMe, t + 1);
            }
        }
    };
    if (l == 0) run(IC<4>{});
    else        run(IC<8>{});

    // ---- epilogue: retire final ring stores, post last prod
    if (l < 3) {
        asm volatile("s_waitcnt vmcnt(0)" ::: "memory");
        __syncthreads();
        if (tid == 0) post_flag(prodMe, Tn - 1);
    }
}

extern "C" void kernel_launch(void* const* d_in, const int* in_sizes, int n_in,
                              void* d_out, int out_size, void* d_ws, size_t ws_size,
                              hipStream_t stream) {
    const float* x    = (const float*)d_in[0];
    const float* h0   = (const float*)d_in[1];
    const float* c0   = (const float*)d_in[2];
    const float* Wih0 = (const float*)d_in[3];
    const float* Wih  = (const float*)d_in[4];
    const float* Whh  = (const float*)d_in[5];
    const float* bih  = (const float*)d_in[6];
    const float* bhh  = (const float*)d_in[7];
    const float* Wlin = (const float*)d_in[8];
    const float* blin = (const float*)d_in[9];
    float* out = (float*)d_out;

    hipLaunchKernelGGL(init_kernel, dim3(1), dim3(256), 0, stream);
    hipLaunchKernelGGL(lstm_kernel, dim3(NBLK), dim3(THR), 0, stream,
                       x, h0, c0, Wih0, Wih, Whh, bih, bhh, Wlin, blin, out);
}

// Round 10
// 1533.838 us; speedup vs baseline: 9.3478x; 1.1067x over previous
//
#include <hip/hip_runtime.h>
#include <hip/hip_fp16.h>
#include <math.h>

#define Tn 1024
#define Bn 256
#define Hn 120
#define Ln 4
#define NBC 16                // batch chunks of 16
#define NBCOL 16              // cols per chunk
#define NBLK (Ln*NBC)         // 64 blocks
#define THR 512               // 8 waves
#define Dd 16                 // ring depth
#define PADI 32
#define KPh 520               // col stride u16: 260 dwords, %32==4 -> 2-way (free)
#define ENT 2048              // ring entry u16: 8w*16col*4quad*4m

typedef _Float16 f16x8 __attribute__((ext_vector_type(8)));
typedef float    f32x4 __attribute__((ext_vector_type(4)));
typedef unsigned int u32x2 __attribute__((ext_vector_type(2)));
typedef unsigned short ushort_t;

template<int N> struct IC { static constexpr int value = N; };

// R23: critical-path slimming at fixed geometry (col-scaling exhausted:
// n_tiles=1, trans/SIMD invariant under further col splits).
// (1) SINGLE barrier/step: bh double-buffer (4 regions per col: h ping
//     0..127, bh ping 128..255, h pong 256..383, bh pong 384..511) ->
//     staging(t+1) writes a region disjoint from ALL step-t readers.
// (2) ring stores from REGISTERS in producer order [w][col][quad][m];
//     consumer stages linearly; A-fragments re-gathered at init with
//     the inverse permutation (k-slot 128+s <-> cell via invpi(s)).
//     Pad slots (w>=6,m=3): A=0 and producer stores 0.0 (NaN-safe).
// (3) counted drain vmcnt(1) (l<3): FIFO [store(t-1), load(t+1),
//     store(t)] -> retires old store + entry load, fresh store flies.
//     l==3: vmcnt(0) (stale out-store + load only).
// (4) l0 x lives in h-region pad slot 120 (KTL stays 4).
// Protocol (batch-4 flags, Dd=16, entry-issued loads) unchanged.
__device__ ushort_t g_ring[(size_t)3 * Dd * NBC * ENT];
__device__ int g_prod[3 * NBC * PADI];
__device__ int g_cons[Ln * NBC * PADI];
__device__ int g_abort;

__global__ __launch_bounds__(256) void init_kernel() {
    int idx = threadIdx.x;
    if (idx < 3 * NBC)  g_prod[idx * PADI] = -1;
    if (idx < Ln * NBC) g_cons[idx * PADI] = -1;
    if (idx == 0)       g_abort = 0;
}

#if __has_builtin(__builtin_amdgcn_exp2f)
__device__ __forceinline__ float hw_exp2(float x) { return __builtin_amdgcn_exp2f(x); }
#else
__device__ __forceinline__ float hw_exp2(float x) { return exp2f(x); }
#endif
#if __has_builtin(__builtin_amdgcn_rcpf)
__device__ __forceinline__ float hw_rcp(float x) { return __builtin_amdgcn_rcpf(x); }
#else
__device__ __forceinline__ float hw_rcp(float x) { return 1.0f / x; }
#endif
#define LOG2E_F 1.44269504f

__device__ __forceinline__ float sigm(float v) {
    return hw_rcp(1.0f + hw_exp2(-LOG2E_F * v));
}
__device__ __forceinline__ float tanh_fast(float v) {
    return 1.0f - 2.0f * hw_rcp(1.0f + hw_exp2(2.0f * LOG2E_F * v));
}

// raw barrier: waits LDS ops only; vmem stays in flight across it.
#define BAR_LGKM() asm volatile("s_waitcnt lgkmcnt(0)\ns_barrier" ::: "memory")

__device__ __forceinline__ void spin_wait(int* p, int tgt, int& dead, int& pc) {
    if (dead || pc >= tgt) return;
    int guard = 0, v;
    while ((v = __hip_atomic_load(p, __ATOMIC_RELAXED,
                                  __HIP_MEMORY_SCOPE_SYSTEM)) < tgt) {
        __builtin_amdgcn_s_sleep(1);
        if ((++guard & 127) == 0) {
            if (__hip_atomic_load(&g_abort, __ATOMIC_RELAXED,
                                  __HIP_MEMORY_SCOPE_SYSTEM)) { dead = 1; return; }
            if (guard > 60000) { atomicExch(&g_abort, 1); dead = 1; return; }
        }
    }
    pc = v;
}

__device__ __forceinline__ void post_flag(int* p, int v) {
    __hip_atomic_store(p, v, __ATOMIC_RELAXED, __HIP_MEMORY_SCOPE_SYSTEM);
}

__global__ __launch_bounds__(THR, 2) void lstm_kernel(
    const float* __restrict__ x,    const float* __restrict__ h0,
    const float* __restrict__ c0,   const float* __restrict__ Wih0,
    const float* __restrict__ Wih,  const float* __restrict__ Whh,
    const float* __restrict__ bih,  const float* __restrict__ bhh,
    const float* __restrict__ Wlin, const float* __restrict__ blin,
    float* __restrict__ out)
{
    __shared__ _Float16 hxT[NBCOL * KPh];   // 16.6 KB

    const int bx   = blockIdx.x;
    const int l    = bx >> 4;
    const int bc   = bx & 15;
    const int tid  = threadIdx.x;
    const int w    = tid >> 6;
    const int lane = tid & 63;
    const int quad = lane >> 4;
    const int l16  = lane & 15;
    const int bg0  = bc * NBCOL;
    const int mtn  = (w < 6) ? 4 : 3;
    const int mt0  = (w < 6) ? 4 * w : 24 + 3 * (w - 6);
    int dead = 0, pcb = -0x40000000, pca = -0x40000000;

    const float* WhhL = Whh + (size_t)l * 4 * Hn * Hn;
    const float* WihL = (l > 0) ? Wih + (size_t)(l - 1) * 4 * Hn * Hn : Whh;
    ushort_t* ringP = g_ring + (size_t)l * Dd * NBC * ENT;              // l<3
    const ushort_t* ringC =
        g_ring + (size_t)(l > 0 ? l - 1 : 0) * Dd * NBC * ENT;
    int* prodUp = &g_prod[(l > 0 ? ((l - 1) * NBC + bc) : 0) * PADI];
    int* prodMe = &g_prod[(l < 3 ? (l * NBC + bc) : 0) * PADI];
    int* consDn = &g_cons[(l < 3 ? ((l + 1) * NBC + bc) : 0) * PADI];
    int* consMe = &g_cons[(l * NBC + bc) * PADI];

    // ---- persistent A-fragments; k<120: Whh(cell=k); 120..127: pad
    // (l0: k==120 -> Wih0); k>=128: bh slot s=k-128, cell=invpi(s).
    f16x8 a[4][8];
    #pragma unroll
    for (int m = 0; m < 4; ++m) {
        int rp = (mt0 + m) * 16 + l16;          // permuted row 0..479
        int cell = rp >> 2, gate = rp & 3;
        int orow = gate * Hn + cell;
        #pragma unroll
        for (int kt = 0; kt < 8; ++kt) {
            f16x8 av;
            #pragma unroll
            for (int j = 0; j < 8; ++j) {
                int k = kt * 32 + quad * 8 + j;
                float v = 0.f;
                if (m < mtn) {
                    if (k < Hn)          v = WhhL[orow * Hn + k];
                    else if (l == 0)     { if (k == 120) v = Wih0[orow]; }
                    else if (k >= 128) {
                        int s = k - 128, w2 = s >> 4, r = s & 15;
                        int q2 = r >> 2, m2 = r & 3;
                        int mtn2 = (w2 < 6) ? 4 : 3;
                        int mt02 = (w2 < 6) ? 4 * w2 : 24 + 3 * (w2 - 6);
                        if (m2 < mtn2)
                            v = WihL[orow * Hn + (mt02 + m2) * 4 + q2];
                    }
                }
                av[j] = (_Float16)v;
            }
            a[m][kt] = av;
        }
    }

    float bias_g[4][4];
    float cst[4];
    #pragma unroll
    for (int m = 0; m < 4; ++m) {
        int cell = (mt0 + m) * 4 + quad;
        #pragma unroll
        for (int g = 0; g < 4; ++g)
            bias_g[m][g] = (m < mtn)
                ? bih[l * 4 * Hn + g * Hn + cell] + bhh[l * 4 * Hn + g * Hn + cell]
                : 0.f;
        cst[m] = (m < mtn) ? c0[(l * Bn + bg0 + l16) * Hn + cell] : 0.f;
    }

    // consumer staging indices: ring u16 i=tid*4 -> (w2,col,q2,m0..3)
    const int sg_col = (tid >> 2) & 15;
    const int sg_w   = tid >> 6;
    const int sg_q   = tid & 3;
    const int sg_lds = sg_col * KPh + 128 + sg_w * 16 + sg_q * 4; // + parity*256

    const int oc_col = tid >> 3, oc_j = tid & 7;  // l3 out (tid<128)
    float wl[15];
    if (l == 3) {
        #pragma unroll
        for (int c2 = 0; c2 < 15; ++c2) wl[c2] = Wlin[oc_j * 15 + c2];
    }

    // init: zero everything once, then h0 -> pong h region (256+)
    for (int q2 = tid; q2 < NBCOL * KPh; q2 += THR) hxT[q2] = (_Float16)0.f;
    __syncthreads();
    for (int q2 = tid; q2 < NBCOL * Hn; q2 += THR) {
        int col = q2 / Hn, cell = q2 % Hn;
        hxT[col * KPh + 256 + cell] = (_Float16)h0[(l * Bn + bg0 + col) * Hn + cell];
    }
    __syncthreads();

    // ---- prologue: stage bh(0) into bh-ping (128) / x(0) into h-pong pad
    if (l > 0) {
        spin_wait(prodUp, 0, dead, pcb);
        u32x2 v0 = {0, 0};
        const ushort_t* p = ringC + (size_t)(0 * NBC + bc) * ENT + tid * 4;
        asm volatile("global_load_dwordx2 %0, %1, off sc0 sc1"
                     : "=v"(v0) : "v"(p));
        asm volatile("s_waitcnt vmcnt(0)" ::: "memory");
        *(u32x2*)&hxT[sg_lds] = v0;              // parity 0 region
        __syncthreads();
        if (tid == 96) post_flag(consMe, 0);
    } else {
        if (tid < NBCOL) hxT[tid * KPh + 256 + 120] = (_Float16)x[bg0 + tid];
        __syncthreads();
    }

    auto run = [&](auto ktlc) {
        constexpr int KTL = decltype(ktlc)::value;
        for (int t = 0; t < Tn; ++t) {
            const int slotW = t & (Dd - 1);
            const int slotR = (t + 1) & (Dd - 1);
            const int q  = t & 1;
            const int hR = (q ^ 1) << 8;          // h(t-1) region
            const int hW = q << 8;                // h(t) region
            // bh(t) read addr for kt>=4: q*256 + e0 (region 128+q*256)

            if ((t & 3) == 0) {
                if (l > 0) {
                    int tgt = (t + 4 < Tn) ? t + 4 : Tn - 1;
                    spin_wait(prodUp, tgt, dead, pcb);
                }
                if (l < 3 && t >= 16)
                    spin_wait(consDn, t - 13, dead, pca);
            }

            // ---- entry: issue next-step vmem (flies under GEMM+cell)
            u32x2 ld = {0, 0};
            float xr = 0.f;
            if (l > 0 && (t + 1) < Tn) {
                const ushort_t* p = ringC + (size_t)(slotR * NBC + bc) * ENT + tid * 4;
                asm volatile("global_load_dwordx2 %0, %1, off sc0 sc1"
                             : "=v"(ld) : "v"(p));
            }
            if (l == 0 && (t + 1) < Tn && tid < NBCOL)
                xr = x[(t + 1) * Bn + bg0 + tid];

            // ---- GEMM + cell halves; pack h bits for reg-sourced ring store
            f32x4 acc[4];
            #pragma unroll
            for (int m = 0; m < 4; ++m) {
                f32x4 z; z[0] = bias_g[m][0]; z[1] = bias_g[m][1];
                z[2] = bias_g[m][2]; z[3] = bias_g[m][3];
                acc[m] = z;
            }
            unsigned short hb[4] = {0, 0, 0, 0};

            #pragma unroll
            for (int half = 0; half < 2; ++half) {
                const int M0 = half * 2;
                #pragma unroll
                for (int kt = 0; kt < KTL; ++kt) {
                    const int e0 = kt * 32 + quad * 8;
                    const int ao = e0 + ((kt < 4) ? hR : (q << 8));
                    f16x8 bfr = *(const f16x8*)&hxT[l16 * KPh + ao];
                    #pragma unroll
                    for (int m = M0; m < M0 + 2; ++m)
                        if (m < mtn)
                            acc[m] = __builtin_amdgcn_mfma_f32_16x16x32_f16(
                                a[m][kt], bfr, acc[m], 0, 0, 0);
                }
                #pragma unroll
                for (int m = M0; m < M0 + 2; ++m) {
                    if (m >= mtn) continue;
                    int cell = (mt0 + m) * 4 + quad;
                    float ig = sigm(acc[m][0]);
                    float fg = sigm(acc[m][1]);
                    float gg = tanh_fast(acc[m][2]);
                    float og = sigm(acc[m][3]);
                    float cn = fmaf(fg, cst[m], ig * gg);
                    cst[m] = cn;
                    float hn = og * tanh_fast(cn);
                    _Float16 hh = (_Float16)hn;
                    hxT[l16 * KPh + hW + cell] = hh;
                    hb[m] = __builtin_bit_cast(unsigned short, hh);
                }
            }

            // ---- ring store S(t) from regs (producer order; pads are 0)
            if (l < 3) {
                u32x2 sv;
                sv[0] = (unsigned)hb[0] | ((unsigned)hb[1] << 16);
                sv[1] = (unsigned)hb[2] | ((unsigned)hb[3] << 16);
                ushort_t* p0 = ringP + (size_t)(slotW * NBC + bc) * ENT
                             + w * 256 + l16 * 16 + quad * 4;
                asm volatile("global_store_dwordx2 %0, %1, off sc0 sc1"
                             :: "v"(p0), "v"(sv) : "memory");
            }

            // ---- counted drain: retire store(t-1) + entry load, keep S(t)
            if (l < 3) { asm volatile("s_waitcnt vmcnt(1)" ::: "memory"); }
            else       { asm volatile("s_waitcnt vmcnt(0)" ::: "memory"); }
            __builtin_amdgcn_sched_barrier(0);

            // ---- stage bh(t+1)/x(t+1) into the OTHER parity (no reader now)
            if (l > 0 && (t + 1) < Tn)
                *(u32x2*)&hxT[sg_lds + ((q ^ 1) << 8)] = ld;
            if (l == 0 && (t + 1) < Tn && tid < NBCOL)
                hxT[tid * KPh + hW + 120] = (_Float16)xr;

            BAR_LGKM();   // single barrier: h(t) + staged(t+1) visible

            if (l == 3 && tid < NBCOL * 8) {
                float pout = 0.f;
                const _Float16* hrow = &hxT[oc_col * KPh + hW + oc_j * 15];
                #pragma unroll
                for (int c2 = 0; c2 < 15; ++c2)
                    pout = fmaf(wl[c2], (float)hrow[c2], pout);
                pout += __shfl_down(pout, 4, 8);
                pout += __shfl_down(pout, 2, 8);
                pout += __shfl_down(pout, 1, 8);
                if (oc_j == 0) out[t * Bn + bg0 + oc_col] = pout + blin[0];
            }

            if ((t & 3) == 3) {
                if (l < 3 && tid == 0)  post_flag(prodMe, t - 1);
                if (l > 0 && tid == 96) post_flag(consMe, t + 1);
            }
        }
    };
    if (l == 0) run(IC<4>{});
    else        run(IC<8>{});

    // ---- epilogue: retire final ring stores, post last prod
    if (l < 3) {
        asm volatile("s_waitcnt vmcnt(0)" ::: "memory");
        __syncthreads();
        if (tid == 0) post_flag(prodMe, Tn - 1);
    }
}

extern "C" void kernel_launch(void* const* d_in, const int* in_sizes, int n_in,
                              void* d_out, int out_size, void* d_ws, size_t ws_size,
                              hipStream_t stream) {
    const float* x    = (const float*)d_in[0];
    const float* h0   = (const float*)d_in[1];
    const float* c0   = (const float*)d_in[2];
    const float* Wih0 = (const float*)d_in[3];
    const float* Wih  = (const float*)d_in[4];
    const float* Whh  = (const float*)d_in[5];
    const float* bih  = (const float*)d_in[6];
    const float* bhh  = (const float*)d_in[7];
    const float* Wlin = (const float*)d_in[8];
    const float* blin = (const float*)d_in[9];
    float* out = (float*)d_out;

    hipLaunchKernelGGL(init_kernel, dim3(1), dim3(256), 0, stream);
    hipLaunchKernelGGL(lstm_kernel, dim3(NBLK), dim3(THR), 0, stream,
                       x, h0, c0, Wih0, Wih, Whh, bih, bhh, Wlin, blin, out);
}